// Round 1
// baseline (1007.341 us; speedup 1.0000x reference)
//
#include <hip/hip_runtime.h>
#include <math.h>

// Problem constants
//   B=4, NB=2048, NA=NC=1024, D=1024, E=8, H=16, HD=64, TOP_K=2
// R3 lesson: NO lambdas capturing register arrays in hot kernels (scratch spills).
// R4 lesson: transpose-store staging maps must be checked for bank collapse.
// R5: GEMMs on bf16 split-3 MFMA (hi*hi+hi*lo+lo*hi), err ~2^-16 — verified safe.
// R6: attention on split-3 MFMA too. No-max softmax (scores bounded ~2.4, exp safe,
//     result identical after the final division).
// R7: attn LDS 96256->81920 B (pad -> XOR swizzle) for 2 blocks/CU; softmax scale
//     0.125*log2e folded into Q-proj epilogue (bare v_exp); P pack via
//     v_cvt_pk_bf16_f32 + v_perm; P unpack via v_perm. Bank balance re-audited:
//     K/V col8^=(row&7) -> 8 lanes/4-bank group; P col^=((row>>2)&7)<<3 -> 2/bank.

typedef __attribute__((ext_vector_type(8))) short short8;
typedef __attribute__((ext_vector_type(4))) float f32x4;
typedef __attribute__((ext_vector_type(4))) unsigned int u32x4;
typedef unsigned short u16;
typedef unsigned int u32;

// ----------------------------------------------------------------------------
__global__ void zero_k(double* p) {
    if (threadIdx.x < 8) p[threadIdx.x] = 0.0;
}

// ----------------------------------------------------------------------------
// fp32 -> bf16 hi/lo split helpers (RNE)
__device__ inline u16 bf_hi(float x) {
    u32 u = __float_as_uint(x);
    u += 0x7FFFu + ((u >> 16) & 1u);
    return (u16)(u >> 16);
}
__device__ inline u16 bf_lo(float x, u16 h) {
    float hf = __uint_as_float(((u32)h) << 16);
    return bf_hi(x - hf);
}
__device__ inline u32 pack_bf(float x) {
    u32 u = __float_as_uint(x);
    u32 hi = (u + (0x7FFFu + ((u >> 16) & 1u))) >> 16;
    float hf = __uint_as_float(hi << 16);
    float d = x - hf;
    u32 u2 = __float_as_uint(d);
    u32 lo = (u2 + (0x7FFFu + ((u2 >> 16) & 1u))) >> 16;
    return (hi << 16) | lo;
}

// fast pair-pack: two fp32 -> two (hi<<16|lo) u32 via v_cvt_pk_bf16_f32 + v_perm.
// Split-3 is robust to hi rounding mode: lo absorbs hi's rounding residual.
__device__ inline void pack2(float p0, float p1, u32& o0, u32& o1) {
    u32 h01, l01;
    asm("v_cvt_pk_bf16_f32 %0, %1, %2" : "=v"(h01) : "v"(p0), "v"(p1));
    float d0 = p0 - __uint_as_float(h01 << 16);
    float d1 = p1 - __uint_as_float(h01 & 0xffff0000u);
    asm("v_cvt_pk_bf16_f32 %0, %1, %2" : "=v"(l01) : "v"(d0), "v"(d1));
    o0 = __builtin_amdgcn_perm(h01, l01, 0x05040100u);   // [h0|l0]
    o1 = __builtin_amdgcn_perm(h01, l01, 0x07060302u);   // [h1|l1]
}

__global__ __launch_bounds__(256)
void split_k(const float* __restrict__ in, u16* __restrict__ hi,
             u16* __restrict__ lo, int n4) {
    int i = blockIdx.x * 256 + threadIdx.x;
    if (i >= n4) return;
    float4 x = ((const float4*)in)[i];
    ushort4 h, l;
    h.x = bf_hi(x.x); l.x = bf_lo(x.x, h.x);
    h.y = bf_hi(x.y); l.y = bf_lo(x.y, h.y);
    h.z = bf_hi(x.z); l.z = bf_lo(x.z, h.z);
    h.w = bf_hi(x.w); l.w = bf_lo(x.w, h.w);
    ((ushort4*)hi)[i] = h;
    ((ushort4*)lo)[i] = l;
}

// ----------------------------------------------------------------------------
__global__ void emb_k(const int* __restrict__ t, float* __restrict__ emb) {
    int b = blockIdx.x;
    int j = threadIdx.x; // 0..511
    float x1 = (float)(-9.210340371976184) * (float)j;
    float x2 = x1 / 511.0f;
    float freq = (float)exp((double)x2);
    float tf = (float)t[b];
    float arg = tf * freq;
    emb[b * 1024 + j]       = (float)sin((double)arg);
    emb[b * 1024 + 512 + j] = (float)cos((double)arg);
}

// ----------------------------------------------------------------------------
__global__ void te_fc_k(const float* __restrict__ in, const float* __restrict__ W,
                        const float* __restrict__ bias, float* __restrict__ out,
                        int K, int N, int do_silu) {
    int b = blockIdx.x;
    int wv = threadIdx.x >> 6, lane = threadIdx.x & 63;
    const float* inb = in + (size_t)b * K;
    int n0 = blockIdx.y * 16 + wv * 4;
    for (int q = 0; q < 4; q++) {
        int n = n0 + q;
        const float* wr = W + (size_t)n * K;
        float acc = 0.f;
        for (int c = lane * 4; c < K; c += 256) {
            float4 a  = *(const float4*)(inb + c);
            float4 w4 = *(const float4*)(wr + c);
            acc += a.x * w4.x + a.y * w4.y + a.z * w4.z + a.w * w4.w;
        }
#pragma unroll
        for (int off = 1; off < 64; off <<= 1) acc += __shfl_xor(acc, off, 64);
        if (lane == 0) {
            float x = acc + bias[n];
            out[(size_t)b * N + n] = do_silu ? (x / (1.0f + expf(-x))) : x;
        }
    }
}

// ----------------------------------------------------------------------------
// bf16 split-3 MFMA GEMM. C[rr,cc] = (dot(A[rr,:K], W[cc,:K]) + bias) * scale.
// OMODE: 0 = fp32 out (identity rows), 1 = bf16 hi/lo planes (identity),
//        2 = bf16 planes with KV row remap (K proj), 3 = transposed V^T planes
//        (rows = v-col, cols = act rows; bias indexed by ROW).
template<bool GATE, bool RELU, int OMODE>
__global__ __launch_bounds__(256, 2)
void bfgemm_k(const u16* __restrict__ A0h, const u16* __restrict__ A0l,
              const u16* __restrict__ A1h, const u16* __restrict__ A1l,
              const u16* __restrict__ A2h, const u16* __restrict__ A2l,
              const u16* __restrict__ Wh_g, const u16* __restrict__ Wl_g,
              const float* __restrict__ bias, float* __restrict__ C,
              u16* __restrict__ Chi, u16* __restrict__ Clo, int K, float scale)
{
    __shared__ u16 Ah[128 * 32];
    __shared__ u16 Al[128 * 32];
    __shared__ u16 Wh[128 * 32];
    __shared__ u16 Wl[128 * 32];
    const int tid = threadIdx.x;
    const int row0 = blockIdx.x * 128;
    const int col0 = blockIdx.y * 128;
    const int wv = tid >> 6;
    const int lane = tid & 63;
    const int wrow = (wv & 1) * 64;
    const int wcol = (wv >> 1) * 64;
    const int l15 = lane & 15, quad = lane >> 4;

    f32x4 acc[4][4];
#pragma unroll
    for (int i = 0; i < 4; i++)
#pragma unroll
        for (int j = 0; j < 4; j++)
            acc[i][j] = (f32x4){0.f, 0.f, 0.f, 0.f};

    const int ar0 = tid >> 2, ak0 = (tid & 3) * 8;
    const int ar1 = (tid + 256) >> 2, ak1 = ((tid + 256) & 3) * 8;

    for (int kc = 0; kc < K; kc += 32) {
        const u16* pAh = A0h;
        const u16* pAl = A0l;
        int kk = kc;
        int tembseg = 0;
        if (GATE) {
            int seg = kc >> 10;
            if (seg == 1) { pAh = A1h; pAl = A1l; }
            else if (seg == 2) { pAh = A2h; pAl = A2l; tembseg = 1; }
            kk = kc & 1023;
        }
        const int astr = GATE ? 1024 : K;
        int g0 = row0 + ar0, g1 = row0 + ar1;
        if (GATE && tembseg) { g0 >>= 11; g1 >>= 11; }
        uint4 vah0 = *(const uint4*)&pAh[(size_t)g0 * astr + kk + ak0];
        uint4 vah1 = *(const uint4*)&pAh[(size_t)g1 * astr + kk + ak1];
        uint4 val0 = *(const uint4*)&pAl[(size_t)g0 * astr + kk + ak0];
        uint4 val1 = *(const uint4*)&pAl[(size_t)g1 * astr + kk + ak1];
        uint4 vwh0 = *(const uint4*)&Wh_g[(size_t)(col0 + ar0) * K + kc + ak0];
        uint4 vwh1 = *(const uint4*)&Wh_g[(size_t)(col0 + ar1) * K + kc + ak1];
        uint4 vwl0 = *(const uint4*)&Wl_g[(size_t)(col0 + ar0) * K + kc + ak0];
        uint4 vwl1 = *(const uint4*)&Wl_g[(size_t)(col0 + ar1) * K + kc + ak1];
        __syncthreads();
        *(uint4*)&Ah[ar0 * 32 + ak0] = vah0;
        *(uint4*)&Ah[ar1 * 32 + ak1] = vah1;
        *(uint4*)&Al[ar0 * 32 + ak0] = val0;
        *(uint4*)&Al[ar1 * 32 + ak1] = val1;
        *(uint4*)&Wh[ar0 * 32 + ak0] = vwh0;
        *(uint4*)&Wh[ar1 * 32 + ak1] = vwh1;
        *(uint4*)&Wl[ar0 * 32 + ak0] = vwl0;
        *(uint4*)&Wl[ar1 * 32 + ak1] = vwl1;
        __syncthreads();

        short8 a_h[4], a_l[4];
#pragma unroll
        for (int i = 0; i < 4; i++) {
            int r = (wrow + i * 16 + l15) * 32 + quad * 8;
            a_h[i] = *(const short8*)&Ah[r];
            a_l[i] = *(const short8*)&Al[r];
        }
#pragma unroll
        for (int j = 0; j < 4; j++) {
            int c = (wcol + j * 16 + l15) * 32 + quad * 8;
            short8 b_h = *(const short8*)&Wh[c];
            short8 b_l = *(const short8*)&Wl[c];
#pragma unroll
            for (int i = 0; i < 4; i++) {
                acc[i][j] = __builtin_amdgcn_mfma_f32_16x16x32_bf16(a_h[i], b_h, acc[i][j], 0, 0, 0);
                acc[i][j] = __builtin_amdgcn_mfma_f32_16x16x32_bf16(a_h[i], b_l, acc[i][j], 0, 0, 0);
                acc[i][j] = __builtin_amdgcn_mfma_f32_16x16x32_bf16(a_l[i], b_h, acc[i][j], 0, 0, 0);
            }
        }
    }

#pragma unroll
    for (int i = 0; i < 4; i++) {
#pragma unroll
        for (int j = 0; j < 4; j++) {
            int cc = col0 + wcol + j * 16 + l15;
#pragma unroll
            for (int r = 0; r < 4; r++) {
                int rr = row0 + wrow + i * 16 + quad * 4 + r;
                float v = (acc[i][j][r] + ((OMODE == 3) ? bias[rr] : bias[cc])) * scale;
                if (RELU) v = fmaxf(v, 0.f);
                if (OMODE == 0) {
                    C[(size_t)rr * 1024 + cc] = v;
                } else if (OMODE == 1) {
                    u32 pk = pack_bf(v);
                    size_t a = (size_t)rr * 1024 + cc;
                    Chi[a] = (u16)(pk >> 16); Clo[a] = (u16)pk;
                } else if (OMODE == 2) {
                    int orow = ((rr >> 10) & 3) * 2048 + (rr >> 12) * 1024 + (rr & 1023);
                    u32 pk = pack_bf(v);
                    size_t a = (size_t)orow * 1024 + cc;
                    Chi[a] = (u16)(pk >> 16); Clo[a] = (u16)pk;
                } else {
                    int bb2 = (cc >> 10) & 3;
                    int key = (cc >> 12) * 1024 + (cc & 1023);
                    u32 pk = pack_bf(v);
                    size_t a = ((size_t)(bb2 * 1024 + rr)) * 2048 + key;
                    Chi[a] = (u16)(pk >> 16); Clo[a] = (u16)pk;
                }
            }
        }
    }
}

// ----------------------------------------------------------------------------
// MFMA flash attention, split-3 bf16, no-max softmax.
// Block: 512 thr (8 waves), q-tile 256 (32 q/wave), k-tile 64, 32 k-steps.
// LDS 81920 B (2 blocks/CU): P region [256][64] u32 XOR-swizzled (K tiles alias
// its front); V tiles [2][64*64] u16 XOR-swizzled.
// Softmax: Q planes carry 0.125*log2e scale, so p = exp2(s) directly.
__global__ __launch_bounds__(512, 4)
void attn_k(const u16* Qh, const u16* Ql,
            const u16* __restrict__ Kh, const u16* __restrict__ Kl,
            const u16* __restrict__ Vh, const u16* __restrict__ Vl,
            u16* Oh, u16* Ol)
{
    __shared__ u32 Pu[256 * 64];          // 65536 B
    __shared__ u16 Vsm[2][64 * 64];       // 16384 B
    u16* Ksh = (u16*)Pu;
    u16* Ksl = Ksh + 64 * 64;

    const int tid = threadIdx.x;
    const int w = tid >> 6, lane = tid & 63;
    const int l15 = lane & 15, quad = lane >> 4;
    const int bh = blockIdx.x, b = bh >> 4, h = bh & 15;
    const int qw = blockIdx.y * 256 + w * 32;          // local q base of this wave
    const int qrow0 = b * 2048 + qw;                    // global Q plane row base

    // Q A-fragments in registers
    short8 qh_f[2][2], ql_f[2][2];
#pragma unroll
    for (int i = 0; i < 2; i++)
#pragma unroll
        for (int kc = 0; kc < 2; kc++) {
            size_t a = (size_t)(qrow0 + i * 16 + l15) * 1024 + h * 64 + kc * 32 + quad * 8;
            qh_f[i][kc] = *(const short8*)&Qh[a];
            ql_f[i][kc] = *(const short8*)&Ql[a];
        }

    // staging: one ushort8 per plane per thread for K and V (rows of 64 u16,
    // 8 threads x 16B per row, col8 XOR row&7 swizzle)
    const int skey = tid >> 3, sd8 = tid & 7;
    const int lds_kv = skey * 64 + ((sd8 ^ (skey & 7)) << 3);
    const size_t g_k = ((size_t)(b * 2048) + skey) * 1024 + h * 64 + sd8 * 8;
    const size_t g_v = ((size_t)((b * 16 + h) * 64 + skey)) * 2048 + sd8 * 8;

    uint4 pk_h = *(const uint4*)&Kh[g_k];
    uint4 pk_l = *(const uint4*)&Kl[g_k];
    uint4 pv_h = *(const uint4*)&Vh[g_v];
    uint4 pv_l = *(const uint4*)&Vl[g_v];

    f32x4 o[2][4];
#pragma unroll
    for (int i = 0; i < 2; i++)
#pragma unroll
        for (int j = 0; j < 4; j++) o[i][j] = (f32x4){0.f, 0.f, 0.f, 0.f};
    float lsum[2][4] = {};

    for (int kt = 0; kt < 32; kt++) {
        __syncthreads();               // prev PV (P + V reads) complete
        *(uint4*)&Ksh[lds_kv] = pk_h;
        *(uint4*)&Ksl[lds_kv] = pk_l;
        *(uint4*)&Vsm[0][lds_kv] = pv_h;
        *(uint4*)&Vsm[1][lds_kv] = pv_l;
        __syncthreads();               // staging visible
        if (kt < 31) {
            size_t gk2 = g_k + (size_t)(kt + 1) * 65536;
            size_t gv2 = g_v + (size_t)(kt + 1) * 64;
            pk_h = *(const uint4*)&Kh[gk2];
            pk_l = *(const uint4*)&Kl[gk2];
            pv_h = *(const uint4*)&Vh[gv2];
            pv_l = *(const uint4*)&Vl[gv2];
        }
        // QK^T
        f32x4 s[2][4];
#pragma unroll
        for (int i = 0; i < 2; i++)
#pragma unroll
            for (int j = 0; j < 4; j++) s[i][j] = (f32x4){0.f, 0.f, 0.f, 0.f};
#pragma unroll
        for (int j = 0; j < 4; j++) {
            int ka = (j * 16 + l15) * 64 + ((quad ^ (l15 & 7)) << 3);
            short8 kh0 = *(const short8*)&Ksh[ka];
            short8 kh1 = *(const short8*)&Ksh[ka ^ 32];
            short8 kl0 = *(const short8*)&Ksl[ka];
            short8 kl1 = *(const short8*)&Ksl[ka ^ 32];
#pragma unroll
            for (int i = 0; i < 2; i++) {
                s[i][j] = __builtin_amdgcn_mfma_f32_16x16x32_bf16(qh_f[i][0], kh0, s[i][j], 0, 0, 0);
                s[i][j] = __builtin_amdgcn_mfma_f32_16x16x32_bf16(qh_f[i][0], kl0, s[i][j], 0, 0, 0);
                s[i][j] = __builtin_amdgcn_mfma_f32_16x16x32_bf16(ql_f[i][0], kh0, s[i][j], 0, 0, 0);
                s[i][j] = __builtin_amdgcn_mfma_f32_16x16x32_bf16(qh_f[i][1], kh1, s[i][j], 0, 0, 0);
                s[i][j] = __builtin_amdgcn_mfma_f32_16x16x32_bf16(qh_f[i][1], kl1, s[i][j], 0, 0, 0);
                s[i][j] = __builtin_amdgcn_mfma_f32_16x16x32_bf16(ql_f[i][1], kh1, s[i][j], 0, 0, 0);
            }
        }
        __syncthreads();               // all K reads done -> K region becomes P
        // p = exp2(s) (scale folded into Q) + pair-pack hi/lo + store P + lsum
#pragma unroll
        for (int i = 0; i < 2; i++)
#pragma unroll
            for (int j = 0; j < 4; j++) {
                float p0 = exp2f(s[i][j][0]);
                float p1 = exp2f(s[i][j][1]);
                float p2 = exp2f(s[i][j][2]);
                float p3 = exp2f(s[i][j][3]);
                lsum[i][0] += p0; lsum[i][1] += p1;
                lsum[i][2] += p2; lsum[i][3] += p3;
                u32 o0, o1, o2, o3;
                pack2(p0, p1, o0, o1);
                pack2(p2, p3, o2, o3);
                int rb = w * 32 + i * 16 + quad * 4;
                int csw = (j * 16 + l15) ^ ((i * 4 + quad) << 3);
                Pu[(rb + 0) * 64 + csw] = o0;
                Pu[(rb + 1) * 64 + csw] = o1;
                Pu[(rb + 2) * 64 + csw] = o2;
                Pu[(rb + 3) * 64 + csw] = o3;
            }
        // each wave reads only its own P rows -> in-wave DS ordering suffices
#pragma unroll
        for (int kc = 0; kc < 2; kc++) {
            short8 ph[2], pl[2];
#pragma unroll
            for (int i = 0; i < 2; i++) {
                int prow = w * 32 + i * 16 + l15;
                int pcol = (kc * 32 + quad * 8) ^ ((i * 4 + (l15 >> 2)) << 3);
                const uint4* pp = (const uint4*)&Pu[prow * 64 + pcol];
                uint4 u0 = pp[0], u1 = pp[1];
                union { short8 s; u32x4 u; } hh, ll;
                hh.u = (u32x4){ __builtin_amdgcn_perm(u0.y, u0.x, 0x07060302u),
                                __builtin_amdgcn_perm(u0.w, u0.z, 0x07060302u),
                                __builtin_amdgcn_perm(u1.y, u1.x, 0x07060302u),
                                __builtin_amdgcn_perm(u1.w, u1.z, 0x07060302u) };
                ll.u = (u32x4){ __builtin_amdgcn_perm(u0.y, u0.x, 0x05040100u),
                                __builtin_amdgcn_perm(u0.w, u0.z, 0x05040100u),
                                __builtin_amdgcn_perm(u1.y, u1.x, 0x05040100u),
                                __builtin_amdgcn_perm(u1.w, u1.z, 0x05040100u) };
                ph[i] = hh.s; pl[i] = ll.s;
            }
#pragma unroll
            for (int jd = 0; jd < 4; jd++) {
                int va = (jd * 16 + l15) * 64 + ((((kc << 2) + quad) ^ (l15 & 7)) << 3);
                short8 vvh = *(const short8*)&Vsm[0][va];
                short8 vvl = *(const short8*)&Vsm[1][va];
#pragma unroll
                for (int i = 0; i < 2; i++) {
                    o[i][jd] = __builtin_amdgcn_mfma_f32_16x16x32_bf16(ph[i], vvh, o[i][jd], 0, 0, 0);
                    o[i][jd] = __builtin_amdgcn_mfma_f32_16x16x32_bf16(ph[i], vvl, o[i][jd], 0, 0, 0);
                    o[i][jd] = __builtin_amdgcn_mfma_f32_16x16x32_bf16(pl[i], vvh, o[i][jd], 0, 0, 0);
                }
            }
        }
    }
    // reduce lsum across the 16 key-lanes (xor 1,2,4,8 stay within quad rows)
#pragma unroll
    for (int i = 0; i < 2; i++)
#pragma unroll
        for (int r = 0; r < 4; r++) {
            float s2 = lsum[i][r];
            s2 += __shfl_xor(s2, 1, 64);
            s2 += __shfl_xor(s2, 2, 64);
            s2 += __shfl_xor(s2, 4, 64);
            s2 += __shfl_xor(s2, 8, 64);
            lsum[i][r] = s2;
        }
    // epilogue: ctx = o / l -> bf16 hi/lo planes (overwrites this block's Q region)
#pragma unroll
    for (int i = 0; i < 2; i++)
#pragma unroll
        for (int jd = 0; jd < 4; jd++)
#pragma unroll
            for (int r = 0; r < 4; r++) {
                float v = o[i][jd][r] / lsum[i][r];
                u32 pk = pack_bf(v);
                size_t a = (size_t)(qrow0 + i * 16 + quad * 4 + r) * 1024 + h * 64 + jd * 16 + l15;
                Oh[a] = (u16)(pk >> 16);
                Ol[a] = (u16)pk;
            }
}

// ----------------------------------------------------------------------------
// layernorm(X + T) * g + b, emitting bf16 hi/lo planes for the gate GEMM
__global__ __launch_bounds__(256)
void ln_split_k(const float* __restrict__ X, const float* __restrict__ T,
                const float* __restrict__ g, const float* __restrict__ bta,
                u16* __restrict__ chi, u16* __restrict__ clo)
{
    __shared__ float red[8];
    int r = blockIdx.x, tid = threadIdx.x;
    size_t base = (size_t)r * 1024 + tid * 4;
    float4 x  = *(const float4*)(X + base);
    float4 tk = *(const float4*)(T + base);
    x.x += tk.x; x.y += tk.y; x.z += tk.z; x.w += tk.w;
    float s = x.x + x.y + x.z + x.w;
#pragma unroll
    for (int off = 1; off < 64; off <<= 1) s += __shfl_xor(s, off, 64);
    int wv = tid >> 6;
    if ((tid & 63) == 0) red[wv] = s;
    __syncthreads();
    float mu = (red[0] + red[1] + red[2] + red[3]) * (1.0f / 1024.0f);
    float dx0 = x.x - mu, dx1 = x.y - mu, dx2 = x.z - mu, dx3 = x.w - mu;
    float ss = dx0 * dx0 + dx1 * dx1 + dx2 * dx2 + dx3 * dx3;
#pragma unroll
    for (int off = 1; off < 64; off <<= 1) ss += __shfl_xor(ss, off, 64);
    if ((tid & 63) == 0) red[4 + wv] = ss;
    __syncthreads();
    float var = (red[4] + red[5] + red[6] + red[7]) * (1.0f / 1024.0f);
    float inv = 1.0f / sqrtf(var + 1e-5f);
    float4 gg = *(const float4*)(g + tid * 4);
    float4 bb = *(const float4*)(bta + tid * 4);
    float y0 = dx0 * inv * gg.x + bb.x;
    float y1 = dx1 * inv * gg.y + bb.y;
    float y2 = dx2 * inv * gg.z + bb.z;
    float y3 = dx3 * inv * gg.w + bb.w;
    ushort4 h, l;
    h.x = bf_hi(y0); l.x = bf_lo(y0, h.x);
    h.y = bf_hi(y1); l.y = bf_lo(y1, h.y);
    h.z = bf_hi(y2); l.z = bf_lo(y2, h.z);
    h.w = bf_hi(y3); l.w = bf_lo(y3, h.w);
    *(ushort4*)&chi[base] = h;
    *(ushort4*)&clo[base] = l;
}

// ----------------------------------------------------------------------------
__global__ __launch_bounds__(256)
void logits_k(const float* __restrict__ Hd, const float* __restrict__ W2,
              const float* __restrict__ b2, const float* __restrict__ eb,
              float* __restrict__ Lg)
{
    int gw = (blockIdx.x * 256 + threadIdx.x) >> 6;  // row 0..8191
    int lane = threadIdx.x & 63;
    const float* h = Hd + (size_t)gw * 1024;
    float4 hv[4];
#pragma unroll
    for (int j = 0; j < 4; j++) hv[j] = *(const float4*)(h + j * 256 + lane * 4);
    float res[8];
#pragma unroll
    for (int e = 0; e < 8; e++) {
        const float* w = W2 + (size_t)e * 1024;
        float acc = 0.f;
#pragma unroll
        for (int j = 0; j < 4; j++) {
            float4 w4 = *(const float4*)(w + j * 256 + lane * 4);
            acc += hv[j].x * w4.x + hv[j].y * w4.y + hv[j].z * w4.z + hv[j].w * w4.w;
        }
#pragma unroll
        for (int off = 1; off < 64; off <<= 1) acc += __shfl_xor(acc, off, 64);
        res[e] = acc;
    }
    if (lane < 8) {
        float v = res[0];
#pragma unroll
        for (int e = 1; e < 8; e++) v = (lane == e) ? res[e] : v;
        Lg[(size_t)gw * 8 + lane] = v + b2[lane] + eb[lane];
    }
}

// ----------------------------------------------------------------------------
__global__ __launch_bounds__(256)
void router_k(const float* __restrict__ Lg, const int* __restrict__ t,
              float* __restrict__ outp, double* __restrict__ loadAcc)
{
    __shared__ double wred[4][8];
    int tid = threadIdx.x;
    int r = blockIdx.x * 256 + tid;   // 0..8191
    int b = r >> 11;
    float tn  = (float)t[b] / 1000.0f;
    float tau = 0.5f + 1.5f * tn;
    float p[8];
    float mx = -INFINITY;
#pragma unroll
    for (int e = 0; e < 8; e++) { p[e] = Lg[(size_t)r * 8 + e] / tau; mx = fmaxf(mx, p[e]); }
    float sum = 0.f;
#pragma unroll
    for (int e = 0; e < 8; e++) { p[e] = expf(p[e] - mx); sum += p[e]; }
#pragma unroll
    for (int e = 0; e < 8; e++) p[e] = p[e] / sum;
#pragma unroll
    for (int e = 0; e < 8; e++) p[e] = 0.85f * p[e] + 0.01875f;   // (1-ALPHA)p + ALPHA/E
    float w = 0.1f + 0.1f * tn;
    float shared_p = fmaxf(p[0], w);
    float osum = 0.f;
#pragma unroll
    for (int e = 1; e < 8; e++) osum += p[e];
    float denom_o = fmaxf(osum, 1e-8f);
    float one_m = 1.0f - shared_p;
    p[0] = shared_p;
#pragma unroll
    for (int e = 1; e < 8; e++) p[e] = (p[e] / denom_o) * one_m;  // match np op order
    int i0 = 0; float v0 = p[0];
#pragma unroll
    for (int e = 1; e < 8; e++) if (p[e] > v0) { v0 = p[e]; i0 = e; }
    int i1 = -1; float v1 = -INFINITY;
#pragma unroll
    for (int e = 0; e < 8; e++) if (e != i0 && p[e] > v1) { v1 = p[e]; i1 = e; }
    float cap = 0.5f + 0.1f * tn;
    float dsp[8], capped[8], hr[8];
    float exsum = 0.f, hsum = 0.f;
#pragma unroll
    for (int e = 0; e < 8; e++) {
        float d = ((e == i0) ? v0 : 0.f) + ((e == i1) ? v1 : 0.f);
        float ex = fmaxf(d - cap, 0.f);
        float c = d - ex;
        float hh = fmaxf(cap - c, 0.f);
        capped[e] = c; hr[e] = hh;
        exsum += ex; hsum += hh;
    }
    float hden = fmaxf(hsum, 1e-8f);
    float dsum = 0.f;
#pragma unroll
    for (int e = 0; e < 8; e++) {
        float d = capped[e] + exsum * (hr[e] / hden);
        dsp[e] = d; dsum += d;
    }
    float cden = dsum + 1e-8f;
#pragma unroll
    for (int e = 0; e < 8; e++) {
        outp[(size_t)r * 8 + e] = dsp[e];
        outp[65536 + (size_t)r * 8 + e] = dsp[e] / cden;
    }
    int lane = tid & 63, wv = tid >> 6;
#pragma unroll
    for (int e = 0; e < 8; e++) {
        double s = (double)dsp[e];
#pragma unroll
        for (int off = 1; off < 64; off <<= 1) s += __shfl_xor(s, off, 64);
        if (lane == 0) wred[wv][e] = s;
    }
    __syncthreads();
    if (tid < 8) {
        double s = wred[0][tid] + wred[1][tid] + wred[2][tid] + wred[3][tid];
        atomicAdd(&loadAcc[tid], s);
    }
}

// ----------------------------------------------------------------------------
__global__ void penalty_k(const double* __restrict__ loadAcc, float* __restrict__ outp) {
    if (threadIdx.x == 0) {
        const float thr = (float)(2048.0 / 7.0 * 1.5);  // fair * 1.5
        float pen = 0.f;
#pragma unroll
        for (int e = 1; e < 8; e++) {
            float load = (float)(loadAcc[e] / 4.0);     // mean over B
            float x = fmaxf(load - thr, 0.f);
            pen += x * x;
        }
        outp[131072] = 0.01f * pen;
    }
}

// ----------------------------------------------------------------------------
extern "C" void kernel_launch(void* const* d_in, const int* in_sizes, int n_in,
                              void* d_out, int out_size, void* d_ws, size_t ws_size,
                              hipStream_t stream)
{
    const float* tokens = (const float*)d_in[0];
    const float* outA   = (const float*)d_in[1];
    const float* outC   = (const float*)d_in[2];
    const int*   tt     = (const int*)  d_in[3];
    const float* in_w   = (const float*)d_in[4];
    const float* in_b   = (const float*)d_in[5];
    const float* op_w   = (const float*)d_in[6];
    const float* op_b   = (const float*)d_in[7];
    const float* lng    = (const float*)d_in[8];
    const float* lnb    = (const float*)d_in[9];
    const float* te_w1  = (const float*)d_in[10];
    const float* te_b1  = (const float*)d_in[11];
    const float* te_w2  = (const float*)d_in[12];
    const float* te_b2  = (const float*)d_in[13];
    const float* g_w1   = (const float*)d_in[14];
    const float* g_b1   = (const float*)d_in[15];
    const float* g_w2   = (const float*)d_in[16];
    const float* g_b2   = (const float*)d_in[17];
    const float* e_bias = (const float*)d_in[18];
    float* out = (float*)d_out;

    float* ws = (float*)d_ws;
    const size_t NM = (size_t)8192 * 1024;
    float* F0     = ws;                  // out_proj result, then gate hidden (fp32)
    float* temb   = ws + NM;             // 4x1024 fp32
    float* embb   = temb + 4096;
    float* hte    = embb + 4096;         // 4x2048
    float* logitsb = hte + 8192;         // 8192x8
    double* loads = (double*)(logitsb + 65536);   // 8 doubles (+pad)

    u16* U = (u16*)(loads + 16);
    u16* Tokh = U;                 // tokens planes (alive whole launch)
    u16* Tokl = Tokh + NM;
    u16* ActH = Tokl + NM;         // [outA;outC] planes for K/V GEMMs
    u16* ActL = ActH + NM;
    u16* Qh   = ActL + NM;         // Q planes -> attn ctx planes (block-disjoint alias)
    u16* Ql   = Qh + NM;
    u16* Kh   = Ql + NM;           // K planes -> later LN(ctx_B) planes
    u16* Kl   = Kh + NM;
    u16* Vth  = Kl + NM;           // V^T planes [b][h][d][2048]
    u16* Vtl  = Vth + NM;
    u16* Wsh  = Vtl + NM;          // weight planes (up to 3M elems)
    u16* Wsl  = Wsh + (size_t)3 * 1024 * 1024;
    u16* Tbh  = Wsl + (size_t)3 * 1024 * 1024;   // temb planes, 4096
    u16* Tbl  = Tbh + 4096;

    zero_k<<<1, 64, 0, stream>>>(loads);
    emb_k<<<4, 512, 0, stream>>>(tt, embb);
    te_fc_k<<<dim3(4, 128), 256, 0, stream>>>(embb, te_w1, te_b1, hte, 1024, 2048, 1);
    te_fc_k<<<dim3(4, 64),  256, 0, stream>>>(hte,  te_w2, te_b2, temb, 2048, 1024, 0);

    split_k<<<8192, 256, 0, stream>>>(tokens, Tokh, Tokl, 8192 * 1024 / 4);
    split_k<<<3072, 256, 0, stream>>>(in_w, Wsh, Wsl, 3 * 1024 * 1024 / 4);
    split_k<<<4096, 256, 0, stream>>>(outA, ActH, ActL, 4096 * 1024 / 4);
    split_k<<<4096, 256, 0, stream>>>(outC, ActH + (size_t)4096 * 1024,
                                      ActL + (size_t)4096 * 1024, 4096 * 1024 / 4);

    // q = (tokens @ wq.T + bq) * (0.125*log2e) -> Q planes (softmax scale folded)
    bfgemm_k<false, false, 1><<<dim3(64, 8), 256, 0, stream>>>(
        Tokh, Tokl, nullptr, nullptr, nullptr, nullptr,
        Wsh, Wsl, in_b, nullptr, Qh, Ql, 1024, 0.18033688011112042f);
    // k -> K planes with per-batch concat row remap
    bfgemm_k<false, false, 2><<<dim3(64, 8), 256, 0, stream>>>(
        ActH, ActL, nullptr, nullptr, nullptr, nullptr,
        Wsh + (size_t)1024 * 1024, Wsl + (size_t)1024 * 1024,
        in_b + 1024, nullptr, Kh, Kl, 1024, 1.0f);
    // v^T: operands swapped (A = wv rows, "W" = act rows) -> transposed planes
    bfgemm_k<false, false, 3><<<dim3(8, 64), 256, 0, stream>>>(
        Wsh + (size_t)2048 * 1024, Wsl + (size_t)2048 * 1024,
        nullptr, nullptr, nullptr, nullptr,
        ActH, ActL, in_b + 2048, nullptr, Vth, Vtl, 1024, 1.0f);

    attn_k<<<dim3(64, 8), 512, 0, stream>>>(Qh, Ql, Kh, Kl, Vth, Vtl, Qh, Ql);

    // out_proj: ctx planes (in Qh/Ql) @ op_w -> fp32 F0
    split_k<<<1024, 256, 0, stream>>>(op_w, Wsh, Wsl, 1024 * 1024 / 4);
    bfgemm_k<false, false, 0><<<dim3(64, 8), 256, 0, stream>>>(
        Qh, Ql, nullptr, nullptr, nullptr, nullptr,
        Wsh, Wsl, op_b, F0, nullptr, nullptr, 1024, 1.0f);

    // ctx_B = LN(out_proj + tokens) -> planes (reuse K planes)
    ln_split_k<<<8192, 256, 0, stream>>>(F0, tokens, lng, lnb, Kh, Kl);

    // gate hidden = relu([tokens | ctx_B | t_emb] @ g_w1.T + b1) -> F0
    split_k<<<4, 256, 0, stream>>>(temb, Tbh, Tbl, 4096 / 4);
    split_k<<<3072, 256, 0, stream>>>(g_w1, Wsh, Wsl, 3072 * 1024 / 4);
    bfgemm_k<true, true, 0><<<dim3(64, 8), 256, 0, stream>>>(
        Tokh, Tokl, Kh, Kl, Tbh, Tbl,
        Wsh, Wsl, g_b1, F0, nullptr, nullptr, 3072, 1.0f);

    logits_k<<<2048, 256, 0, stream>>>(F0, g_w2, g_b2, e_bias, logitsb);
    router_k<<<32, 256, 0, stream>>>(logitsb, tt, out, loads);
    penalty_k<<<1, 64, 0, stream>>>(loads, out);
}

// Round 2
// 858.972 us; speedup vs baseline: 1.1727x; 1.1727x over previous
//
#include <hip/hip_runtime.h>
#include <math.h>

// Problem constants
//   B=4, NB=2048, NA=NC=1024, D=1024, E=8, H=16, HD=64, TOP_K=2
// R3 lesson: NO lambdas capturing register arrays in hot kernels (scratch spills).
// R4 lesson: transpose-store staging maps must be checked for bank collapse.
// R5: GEMMs on bf16 split-3 MFMA (hi*hi+hi*lo+lo*hi), err ~2^-16 — verified safe.
// R6: attention on split-3 MFMA. No-max softmax (scores bounded ~2.4, exp safe).
// R7 LESSON: __launch_bounds__(512,4) forced a 128-reg cap < ~150 live -> 1.4 GB
//     scratch spill, 263->418us. NEVER force occupancy past natural reg demand.
//     VALU cuts (exp2-folded scale, cvt_pk pack, perm unpack) verified correct.
// R8: attn restructured to 256-thr blocks (4 waves, q-tile 128), LDS 49152 B ->
//     3 blocks/CU natural. K/V staged via global_load_lds (width 16): linear LDS
//     dest + pre-swizzled GLOBAL source col8^=(row&7); read-side swizzles
//     unchanged (rule: swizzle both sides or neither). No prefetch regs.

typedef __attribute__((ext_vector_type(8))) short short8;
typedef __attribute__((ext_vector_type(4))) float f32x4;
typedef __attribute__((ext_vector_type(4))) unsigned int u32x4;
typedef unsigned short u16;
typedef unsigned int u32;

// ----------------------------------------------------------------------------
__global__ void zero_k(double* p) {
    if (threadIdx.x < 8) p[threadIdx.x] = 0.0;
}

// ----------------------------------------------------------------------------
// fp32 -> bf16 hi/lo split helpers (RNE)
__device__ inline u16 bf_hi(float x) {
    u32 u = __float_as_uint(x);
    u += 0x7FFFu + ((u >> 16) & 1u);
    return (u16)(u >> 16);
}
__device__ inline u16 bf_lo(float x, u16 h) {
    float hf = __uint_as_float(((u32)h) << 16);
    return bf_hi(x - hf);
}
__device__ inline u32 pack_bf(float x) {
    u32 u = __float_as_uint(x);
    u32 hi = (u + (0x7FFFu + ((u >> 16) & 1u))) >> 16;
    float hf = __uint_as_float(hi << 16);
    float d = x - hf;
    u32 u2 = __float_as_uint(d);
    u32 lo = (u2 + (0x7FFFu + ((u2 >> 16) & 1u))) >> 16;
    return (hi << 16) | lo;
}

// fast pair-pack: two fp32 -> two (hi<<16|lo) u32 via v_cvt_pk_bf16_f32 + v_perm.
// Split-3 is robust to hi rounding mode: lo absorbs hi's rounding residual.
__device__ inline void pack2(float p0, float p1, u32& o0, u32& o1) {
    u32 h01, l01;
    asm("v_cvt_pk_bf16_f32 %0, %1, %2" : "=v"(h01) : "v"(p0), "v"(p1));
    float d0 = p0 - __uint_as_float(h01 << 16);
    float d1 = p1 - __uint_as_float(h01 & 0xffff0000u);
    asm("v_cvt_pk_bf16_f32 %0, %1, %2" : "=v"(l01) : "v"(d0), "v"(d1));
    o0 = __builtin_amdgcn_perm(h01, l01, 0x05040100u);   // [h0|l0]
    o1 = __builtin_amdgcn_perm(h01, l01, 0x07060302u);   // [h1|l1]
}

// async global->LDS, 16B per lane. LDS dest = wave-uniform base + lane*16.
__device__ inline void async16(const u16* g, u16* l) {
    __builtin_amdgcn_global_load_lds(
        (const __attribute__((address_space(1))) unsigned int*)g,
        (__attribute__((address_space(3))) unsigned int*)l,
        16, 0, 0);
}

__global__ __launch_bounds__(256)
void split_k(const float* __restrict__ in, u16* __restrict__ hi,
             u16* __restrict__ lo, int n4) {
    int i = blockIdx.x * 256 + threadIdx.x;
    if (i >= n4) return;
    float4 x = ((const float4*)in)[i];
    ushort4 h, l;
    h.x = bf_hi(x.x); l.x = bf_lo(x.x, h.x);
    h.y = bf_hi(x.y); l.y = bf_lo(x.y, h.y);
    h.z = bf_hi(x.z); l.z = bf_lo(x.z, h.z);
    h.w = bf_hi(x.w); l.w = bf_lo(x.w, h.w);
    ((ushort4*)hi)[i] = h;
    ((ushort4*)lo)[i] = l;
}

// ----------------------------------------------------------------------------
__global__ void emb_k(const int* __restrict__ t, float* __restrict__ emb) {
    int b = blockIdx.x;
    int j = threadIdx.x; // 0..511
    float x1 = (float)(-9.210340371976184) * (float)j;
    float x2 = x1 / 511.0f;
    float freq = (float)exp((double)x2);
    float tf = (float)t[b];
    float arg = tf * freq;
    emb[b * 1024 + j]       = (float)sin((double)arg);
    emb[b * 1024 + 512 + j] = (float)cos((double)arg);
}

// ----------------------------------------------------------------------------
__global__ void te_fc_k(const float* __restrict__ in, const float* __restrict__ W,
                        const float* __restrict__ bias, float* __restrict__ out,
                        int K, int N, int do_silu) {
    int b = blockIdx.x;
    int wv = threadIdx.x >> 6, lane = threadIdx.x & 63;
    const float* inb = in + (size_t)b * K;
    int n0 = blockIdx.y * 16 + wv * 4;
    for (int q = 0; q < 4; q++) {
        int n = n0 + q;
        const float* wr = W + (size_t)n * K;
        float acc = 0.f;
        for (int c = lane * 4; c < K; c += 256) {
            float4 a  = *(const float4*)(inb + c);
            float4 w4 = *(const float4*)(wr + c);
            acc += a.x * w4.x + a.y * w4.y + a.z * w4.z + a.w * w4.w;
        }
#pragma unroll
        for (int off = 1; off < 64; off <<= 1) acc += __shfl_xor(acc, off, 64);
        if (lane == 0) {
            float x = acc + bias[n];
            out[(size_t)b * N + n] = do_silu ? (x / (1.0f + expf(-x))) : x;
        }
    }
}

// ----------------------------------------------------------------------------
// bf16 split-3 MFMA GEMM. C[rr,cc] = (dot(A[rr,:K], W[cc,:K]) + bias) * scale.
// OMODE: 0 = fp32 out (identity rows), 1 = bf16 hi/lo planes (identity),
//        2 = bf16 planes with KV row remap (K proj), 3 = transposed V^T planes
//        (rows = v-col, cols = act rows; bias indexed by ROW).
template<bool GATE, bool RELU, int OMODE>
__global__ __launch_bounds__(256, 2)
void bfgemm_k(const u16* __restrict__ A0h, const u16* __restrict__ A0l,
              const u16* __restrict__ A1h, const u16* __restrict__ A1l,
              const u16* __restrict__ A2h, const u16* __restrict__ A2l,
              const u16* __restrict__ Wh_g, const u16* __restrict__ Wl_g,
              const float* __restrict__ bias, float* __restrict__ C,
              u16* __restrict__ Chi, u16* __restrict__ Clo, int K, float scale)
{
    __shared__ u16 Ah[128 * 32];
    __shared__ u16 Al[128 * 32];
    __shared__ u16 Wh[128 * 32];
    __shared__ u16 Wl[128 * 32];
    const int tid = threadIdx.x;
    const int row0 = blockIdx.x * 128;
    const int col0 = blockIdx.y * 128;
    const int wv = tid >> 6;
    const int lane = tid & 63;
    const int wrow = (wv & 1) * 64;
    const int wcol = (wv >> 1) * 64;
    const int l15 = lane & 15, quad = lane >> 4;

    f32x4 acc[4][4];
#pragma unroll
    for (int i = 0; i < 4; i++)
#pragma unroll
        for (int j = 0; j < 4; j++)
            acc[i][j] = (f32x4){0.f, 0.f, 0.f, 0.f};

    const int ar0 = tid >> 2, ak0 = (tid & 3) * 8;
    const int ar1 = (tid + 256) >> 2, ak1 = ((tid + 256) & 3) * 8;

    for (int kc = 0; kc < K; kc += 32) {
        const u16* pAh = A0h;
        const u16* pAl = A0l;
        int kk = kc;
        int tembseg = 0;
        if (GATE) {
            int seg = kc >> 10;
            if (seg == 1) { pAh = A1h; pAl = A1l; }
            else if (seg == 2) { pAh = A2h; pAl = A2l; tembseg = 1; }
            kk = kc & 1023;
        }
        const int astr = GATE ? 1024 : K;
        int g0 = row0 + ar0, g1 = row0 + ar1;
        if (GATE && tembseg) { g0 >>= 11; g1 >>= 11; }
        uint4 vah0 = *(const uint4*)&pAh[(size_t)g0 * astr + kk + ak0];
        uint4 vah1 = *(const uint4*)&pAh[(size_t)g1 * astr + kk + ak1];
        uint4 val0 = *(const uint4*)&pAl[(size_t)g0 * astr + kk + ak0];
        uint4 val1 = *(const uint4*)&pAl[(size_t)g1 * astr + kk + ak1];
        uint4 vwh0 = *(const uint4*)&Wh_g[(size_t)(col0 + ar0) * K + kc + ak0];
        uint4 vwh1 = *(const uint4*)&Wh_g[(size_t)(col0 + ar1) * K + kc + ak1];
        uint4 vwl0 = *(const uint4*)&Wl_g[(size_t)(col0 + ar0) * K + kc + ak0];
        uint4 vwl1 = *(const uint4*)&Wl_g[(size_t)(col0 + ar1) * K + kc + ak1];
        __syncthreads();
        *(uint4*)&Ah[ar0 * 32 + ak0] = vah0;
        *(uint4*)&Ah[ar1 * 32 + ak1] = vah1;
        *(uint4*)&Al[ar0 * 32 + ak0] = val0;
        *(uint4*)&Al[ar1 * 32 + ak1] = val1;
        *(uint4*)&Wh[ar0 * 32 + ak0] = vwh0;
        *(uint4*)&Wh[ar1 * 32 + ak1] = vwh1;
        *(uint4*)&Wl[ar0 * 32 + ak0] = vwl0;
        *(uint4*)&Wl[ar1 * 32 + ak1] = vwl1;
        __syncthreads();

        short8 a_h[4], a_l[4];
#pragma unroll
        for (int i = 0; i < 4; i++) {
            int r = (wrow + i * 16 + l15) * 32 + quad * 8;
            a_h[i] = *(const short8*)&Ah[r];
            a_l[i] = *(const short8*)&Al[r];
        }
#pragma unroll
        for (int j = 0; j < 4; j++) {
            int c = (wcol + j * 16 + l15) * 32 + quad * 8;
            short8 b_h = *(const short8*)&Wh[c];
            short8 b_l = *(const short8*)&Wl[c];
#pragma unroll
            for (int i = 0; i < 4; i++) {
                acc[i][j] = __builtin_amdgcn_mfma_f32_16x16x32_bf16(a_h[i], b_h, acc[i][j], 0, 0, 0);
                acc[i][j] = __builtin_amdgcn_mfma_f32_16x16x32_bf16(a_h[i], b_l, acc[i][j], 0, 0, 0);
                acc[i][j] = __builtin_amdgcn_mfma_f32_16x16x32_bf16(a_l[i], b_h, acc[i][j], 0, 0, 0);
            }
        }
    }

#pragma unroll
    for (int i = 0; i < 4; i++) {
#pragma unroll
        for (int j = 0; j < 4; j++) {
            int cc = col0 + wcol + j * 16 + l15;
#pragma unroll
            for (int r = 0; r < 4; r++) {
                int rr = row0 + wrow + i * 16 + quad * 4 + r;
                float v = (acc[i][j][r] + ((OMODE == 3) ? bias[rr] : bias[cc])) * scale;
                if (RELU) v = fmaxf(v, 0.f);
                if (OMODE == 0) {
                    C[(size_t)rr * 1024 + cc] = v;
                } else if (OMODE == 1) {
                    u32 pk = pack_bf(v);
                    size_t a = (size_t)rr * 1024 + cc;
                    Chi[a] = (u16)(pk >> 16); Clo[a] = (u16)pk;
                } else if (OMODE == 2) {
                    int orow = ((rr >> 10) & 3) * 2048 + (rr >> 12) * 1024 + (rr & 1023);
                    u32 pk = pack_bf(v);
                    size_t a = (size_t)orow * 1024 + cc;
                    Chi[a] = (u16)(pk >> 16); Clo[a] = (u16)pk;
                } else {
                    int bb2 = (cc >> 10) & 3;
                    int key = (cc >> 12) * 1024 + (cc & 1023);
                    u32 pk = pack_bf(v);
                    size_t a = ((size_t)(bb2 * 1024 + rr)) * 2048 + key;
                    Chi[a] = (u16)(pk >> 16); Clo[a] = (u16)pk;
                }
            }
        }
    }
}

// ----------------------------------------------------------------------------
// MFMA flash attention, split-3 bf16, no-max softmax.
// Block: 256 thr (4 waves), q-tile 128 (32 q/wave), k-tile 64, 32 k-steps.
// LDS 49152 B -> 3 blocks/CU: P region [128][64] u32 XOR-swizzled (K tiles
// alias its front 16KB); V tiles [2][64*64] u16 XOR-swizzled.
// K/V staged via global_load_lds: linear LDS dest, pre-swizzled global source.
// Softmax: Q planes carry 0.125*log2e scale, so p = exp2(s) directly.
__global__ __launch_bounds__(256)
void attn_k(const u16* Qh, const u16* Ql,
            const u16* __restrict__ Kh, const u16* __restrict__ Kl,
            const u16* __restrict__ Vh, const u16* __restrict__ Vl,
            u16* Oh, u16* Ol)
{
    __shared__ u32 Pu[128 * 64];          // 32768 B
    __shared__ u16 Vsm[2][64 * 64];       // 16384 B
    u16* Ksh = (u16*)Pu;
    u16* Ksl = Ksh + 64 * 64;

    const int tid = threadIdx.x;
    const int w = tid >> 6, lane = tid & 63;
    const int l15 = lane & 15, quad = lane >> 4;
    const int bh = blockIdx.x, b = bh >> 4, h = bh & 15;
    const int qw = blockIdx.y * 128 + w * 32;          // local q base of this wave
    const int qrow0 = b * 2048 + qw;                    // global Q plane row base

    // Q A-fragments in registers
    short8 qh_f[2][2], ql_f[2][2];
#pragma unroll
    for (int i = 0; i < 2; i++)
#pragma unroll
        for (int kc = 0; kc < 2; kc++) {
            size_t a = (size_t)(qrow0 + i * 16 + l15) * 1024 + h * 64 + kc * 32 + quad * 8;
            qh_f[i][kc] = *(const short8*)&Qh[a];
            ql_f[i][kc] = *(const short8*)&Ql[a];
        }

    // async-staging maps: thread tid fills linear LDS slot [row=tid>>3][col8=tid&7]
    // (16B each); global source column is pre-swizzled col8^(row&7) so that the
    // read-side swizzled addressing sees K[row][c8] at LDS[row][c8^(row&7)].
    const int srow = tid >> 3;                        // 0..31 (chunk adds +32)
    const int scsw = ((tid & 7) ^ (srow & 7)) << 3;   // swizzled u16 col
    const size_t gk_base = ((size_t)(b * 2048) + srow) * 1024 + h * 64 + scsw;
    const size_t gv_base = ((size_t)((b * 16 + h) * 64 + srow)) * 2048 + scsw;
    u16* ldsK = Ksh + w * 512;            // wave-uniform base (+2048/chunk, +4096 lo)
    u16* ldsV = &Vsm[0][0] + w * 512;

    f32x4 o[2][4];
#pragma unroll
    for (int i = 0; i < 2; i++)
#pragma unroll
        for (int j = 0; j < 4; j++) o[i][j] = (f32x4){0.f, 0.f, 0.f, 0.f};
    float lsum[2][4] = {};

    for (int kt = 0; kt < 32; kt++) {
        __syncthreads();               // prev PV (P + V reads) complete -> tiles free
        {
            const size_t gk = gk_base + (size_t)kt * 65536;   // +64 keys
            const size_t gv = gv_base + (size_t)kt * 64;      // +64 key-cols
            async16(&Kh[gk],         ldsK);                   // rows 0..31
            async16(&Kh[gk + 32768], ldsK + 2048);            // rows 32..63
            async16(&Kl[gk],         ldsK + 4096);
            async16(&Kl[gk + 32768], ldsK + 6144);
            async16(&Vh[gv],         ldsV);                   // d 0..31
            async16(&Vh[gv + 65536], ldsV + 2048);            // d 32..63
            async16(&Vl[gv],         ldsV + 4096);
            async16(&Vl[gv + 65536], ldsV + 6144);
        }
        __syncthreads();               // barrier drains vmcnt -> tiles visible
        // QK^T
        f32x4 s[2][4];
#pragma unroll
        for (int i = 0; i < 2; i++)
#pragma unroll
            for (int j = 0; j < 4; j++) s[i][j] = (f32x4){0.f, 0.f, 0.f, 0.f};
#pragma unroll
        for (int j = 0; j < 4; j++) {
            int ka = (j * 16 + l15) * 64 + ((quad ^ (l15 & 7)) << 3);
            short8 kh0 = *(const short8*)&Ksh[ka];
            short8 kh1 = *(const short8*)&Ksh[ka ^ 32];
            short8 kl0 = *(const short8*)&Ksl[ka];
            short8 kl1 = *(const short8*)&Ksl[ka ^ 32];
#pragma unroll
            for (int i = 0; i < 2; i++) {
                s[i][j] = __builtin_amdgcn_mfma_f32_16x16x32_bf16(qh_f[i][0], kh0, s[i][j], 0, 0, 0);
                s[i][j] = __builtin_amdgcn_mfma_f32_16x16x32_bf16(qh_f[i][0], kl0, s[i][j], 0, 0, 0);
                s[i][j] = __builtin_amdgcn_mfma_f32_16x16x32_bf16(ql_f[i][0], kh0, s[i][j], 0, 0, 0);
                s[i][j] = __builtin_amdgcn_mfma_f32_16x16x32_bf16(qh_f[i][1], kh1, s[i][j], 0, 0, 0);
                s[i][j] = __builtin_amdgcn_mfma_f32_16x16x32_bf16(qh_f[i][1], kl1, s[i][j], 0, 0, 0);
                s[i][j] = __builtin_amdgcn_mfma_f32_16x16x32_bf16(ql_f[i][1], kh1, s[i][j], 0, 0, 0);
            }
        }
        __syncthreads();               // all K reads done -> K region becomes P
        // p = exp2(s) (scale folded into Q) + pair-pack hi/lo + store P + lsum
#pragma unroll
        for (int i = 0; i < 2; i++)
#pragma unroll
            for (int j = 0; j < 4; j++) {
                float p0 = exp2f(s[i][j][0]);
                float p1 = exp2f(s[i][j][1]);
                float p2 = exp2f(s[i][j][2]);
                float p3 = exp2f(s[i][j][3]);
                lsum[i][0] += p0; lsum[i][1] += p1;
                lsum[i][2] += p2; lsum[i][3] += p3;
                u32 o0, o1, o2, o3;
                pack2(p0, p1, o0, o1);
                pack2(p2, p3, o2, o3);
                int rb = w * 32 + i * 16 + quad * 4;
                int csw = (j * 16 + l15) ^ ((i * 4 + quad) << 3);
                Pu[(rb + 0) * 64 + csw] = o0;
                Pu[(rb + 1) * 64 + csw] = o1;
                Pu[(rb + 2) * 64 + csw] = o2;
                Pu[(rb + 3) * 64 + csw] = o3;
            }
        // each wave reads only its own P rows -> in-wave DS ordering suffices
#pragma unroll
        for (int kc = 0; kc < 2; kc++) {
            short8 ph[2], pl[2];
#pragma unroll
            for (int i = 0; i < 2; i++) {
                int prow = w * 32 + i * 16 + l15;
                int pcol = (kc * 32 + quad * 8) ^ ((i * 4 + (l15 >> 2)) << 3);
                const uint4* pp = (const uint4*)&Pu[prow * 64 + pcol];
                uint4 u0 = pp[0], u1 = pp[1];
                union { short8 s; u32x4 u; } hh, ll;
                hh.u = (u32x4){ __builtin_amdgcn_perm(u0.y, u0.x, 0x07060302u),
                                __builtin_amdgcn_perm(u0.w, u0.z, 0x07060302u),
                                __builtin_amdgcn_perm(u1.y, u1.x, 0x07060302u),
                                __builtin_amdgcn_perm(u1.w, u1.z, 0x07060302u) };
                ll.u = (u32x4){ __builtin_amdgcn_perm(u0.y, u0.x, 0x05040100u),
                                __builtin_amdgcn_perm(u0.w, u0.z, 0x05040100u),
                                __builtin_amdgcn_perm(u1.y, u1.x, 0x05040100u),
                                __builtin_amdgcn_perm(u1.w, u1.z, 0x05040100u) };
                ph[i] = hh.s; pl[i] = ll.s;
            }
#pragma unroll
            for (int jd = 0; jd < 4; jd++) {
                int va = (jd * 16 + l15) * 64 + ((((kc << 2) + quad) ^ (l15 & 7)) << 3);
                short8 vvh = *(const short8*)&Vsm[0][va];
                short8 vvl = *(const short8*)&Vsm[1][va];
#pragma unroll
                for (int i = 0; i < 2; i++) {
                    o[i][jd] = __builtin_amdgcn_mfma_f32_16x16x32_bf16(ph[i], vvh, o[i][jd], 0, 0, 0);
                    o[i][jd] = __builtin_amdgcn_mfma_f32_16x16x32_bf16(ph[i], vvl, o[i][jd], 0, 0, 0);
                    o[i][jd] = __builtin_amdgcn_mfma_f32_16x16x32_bf16(pl[i], vvh, o[i][jd], 0, 0, 0);
                }
            }
        }
    }
    // reduce lsum across the 16 key-lanes (xor 1,2,4,8 stay within quad rows)
#pragma unroll
    for (int i = 0; i < 2; i++)
#pragma unroll
        for (int r = 0; r < 4; r++) {
            float s2 = lsum[i][r];
            s2 += __shfl_xor(s2, 1, 64);
            s2 += __shfl_xor(s2, 2, 64);
            s2 += __shfl_xor(s2, 4, 64);
            s2 += __shfl_xor(s2, 8, 64);
            lsum[i][r] = s2;
        }
    // epilogue: ctx = o / l -> bf16 hi/lo planes (overwrites this block's Q region)
#pragma unroll
    for (int i = 0; i < 2; i++)
#pragma unroll
        for (int jd = 0; jd < 4; jd++)
#pragma unroll
            for (int r = 0; r < 4; r++) {
                float v = o[i][jd][r] / lsum[i][r];
                u32 pk = pack_bf(v);
                size_t a = (size_t)(qrow0 + i * 16 + quad * 4 + r) * 1024 + h * 64 + jd * 16 + l15;
                Oh[a] = (u16)(pk >> 16);
                Ol[a] = (u16)pk;
            }
}

// ----------------------------------------------------------------------------
// layernorm(X + T) * g + b, emitting bf16 hi/lo planes for the gate GEMM
__global__ __launch_bounds__(256)
void ln_split_k(const float* __restrict__ X, const float* __restrict__ T,
                const float* __restrict__ g, const float* __restrict__ bta,
                u16* __restrict__ chi, u16* __restrict__ clo)
{
    __shared__ float red[8];
    int r = blockIdx.x, tid = threadIdx.x;
    size_t base = (size_t)r * 1024 + tid * 4;
    float4 x  = *(const float4*)(X + base);
    float4 tk = *(const float4*)(T + base);
    x.x += tk.x; x.y += tk.y; x.z += tk.z; x.w += tk.w;
    float s = x.x + x.y + x.z + x.w;
#pragma unroll
    for (int off = 1; off < 64; off <<= 1) s += __shfl_xor(s, off, 64);
    int wv = tid >> 6;
    if ((tid & 63) == 0) red[wv] = s;
    __syncthreads();
    float mu = (red[0] + red[1] + red[2] + red[3]) * (1.0f / 1024.0f);
    float dx0 = x.x - mu, dx1 = x.y - mu, dx2 = x.z - mu, dx3 = x.w - mu;
    float ss = dx0 * dx0 + dx1 * dx1 + dx2 * dx2 + dx3 * dx3;
#pragma unroll
    for (int off = 1; off < 64; off <<= 1) ss += __shfl_xor(ss, off, 64);
    if ((tid & 63) == 0) red[4 + wv] = ss;
    __syncthreads();
    float var = (red[4] + red[5] + red[6] + red[7]) * (1.0f / 1024.0f);
    float inv = 1.0f / sqrtf(var + 1e-5f);
    float4 gg = *(const float4*)(g + tid * 4);
    float4 bb = *(const float4*)(bta + tid * 4);
    float y0 = dx0 * inv * gg.x + bb.x;
    float y1 = dx1 * inv * gg.y + bb.y;
    float y2 = dx2 * inv * gg.z + bb.z;
    float y3 = dx3 * inv * gg.w + bb.w;
    ushort4 h, l;
    h.x = bf_hi(y0); l.x = bf_lo(y0, h.x);
    h.y = bf_hi(y1); l.y = bf_lo(y1, h.y);
    h.z = bf_hi(y2); l.z = bf_lo(y2, h.z);
    h.w = bf_hi(y3); l.w = bf_lo(y3, h.w);
    *(ushort4*)&chi[base] = h;
    *(ushort4*)&clo[base] = l;
}

// ----------------------------------------------------------------------------
__global__ __launch_bounds__(256)
void logits_k(const float* __restrict__ Hd, const float* __restrict__ W2,
              const float* __restrict__ b2, const float* __restrict__ eb,
              float* __restrict__ Lg)
{
    int gw = (blockIdx.x * 256 + threadIdx.x) >> 6;  // row 0..8191
    int lane = threadIdx.x & 63;
    const float* h = Hd + (size_t)gw * 1024;
    float4 hv[4];
#pragma unroll
    for (int j = 0; j < 4; j++) hv[j] = *(const float4*)(h + j * 256 + lane * 4);
    float res[8];
#pragma unroll
    for (int e = 0; e < 8; e++) {
        const float* w = W2 + (size_t)e * 1024;
        float acc = 0.f;
#pragma unroll
        for (int j = 0; j < 4; j++) {
            float4 w4 = *(const float4*)(w + j * 256 + lane * 4);
            acc += hv[j].x * w4.x + hv[j].y * w4.y + hv[j].z * w4.z + hv[j].w * w4.w;
        }
#pragma unroll
        for (int off = 1; off < 64; off <<= 1) acc += __shfl_xor(acc, off, 64);
        res[e] = acc;
    }
    if (lane < 8) {
        float v = res[0];
#pragma unroll
        for (int e = 1; e < 8; e++) v = (lane == e) ? res[e] : v;
        Lg[(size_t)gw * 8 + lane] = v + b2[lane] + eb[lane];
    }
}

// ----------------------------------------------------------------------------
__global__ __launch_bounds__(256)
void router_k(const float* __restrict__ Lg, const int* __restrict__ t,
              float* __restrict__ outp, double* __restrict__ loadAcc)
{
    __shared__ double wred[4][8];
    int tid = threadIdx.x;
    int r = blockIdx.x * 256 + tid;   // 0..8191
    int b = r >> 11;
    float tn  = (float)t[b] / 1000.0f;
    float tau = 0.5f + 1.5f * tn;
    float p[8];
    float mx = -INFINITY;
#pragma unroll
    for (int e = 0; e < 8; e++) { p[e] = Lg[(size_t)r * 8 + e] / tau; mx = fmaxf(mx, p[e]); }
    float sum = 0.f;
#pragma unroll
    for (int e = 0; e < 8; e++) { p[e] = expf(p[e] - mx); sum += p[e]; }
#pragma unroll
    for (int e = 0; e < 8; e++) p[e] = p[e] / sum;
#pragma unroll
    for (int e = 0; e < 8; e++) p[e] = 0.85f * p[e] + 0.01875f;   // (1-ALPHA)p + ALPHA/E
    float w = 0.1f + 0.1f * tn;
    float shared_p = fmaxf(p[0], w);
    float osum = 0.f;
#pragma unroll
    for (int e = 1; e < 8; e++) osum += p[e];
    float denom_o = fmaxf(osum, 1e-8f);
    float one_m = 1.0f - shared_p;
    p[0] = shared_p;
#pragma unroll
    for (int e = 1; e < 8; e++) p[e] = (p[e] / denom_o) * one_m;  // match np op order
    int i0 = 0; float v0 = p[0];
#pragma unroll
    for (int e = 1; e < 8; e++) if (p[e] > v0) { v0 = p[e]; i0 = e; }
    int i1 = -1; float v1 = -INFINITY;
#pragma unroll
    for (int e = 0; e < 8; e++) if (e != i0 && p[e] > v1) { v1 = p[e]; i1 = e; }
    float cap = 0.5f + 0.1f * tn;
    float dsp[8], capped[8], hr[8];
    float exsum = 0.f, hsum = 0.f;
#pragma unroll
    for (int e = 0; e < 8; e++) {
        float d = ((e == i0) ? v0 : 0.f) + ((e == i1) ? v1 : 0.f);
        float ex = fmaxf(d - cap, 0.f);
        float c = d - ex;
        float hh = fmaxf(cap - c, 0.f);
        capped[e] = c; hr[e] = hh;
        exsum += ex; hsum += hh;
    }
    float hden = fmaxf(hsum, 1e-8f);
    float dsum = 0.f;
#pragma unroll
    for (int e = 0; e < 8; e++) {
        float d = capped[e] + exsum * (hr[e] / hden);
        dsp[e] = d; dsum += d;
    }
    float cden = dsum + 1e-8f;
#pragma unroll
    for (int e = 0; e < 8; e++) {
        outp[(size_t)r * 8 + e] = dsp[e];
        outp[65536 + (size_t)r * 8 + e] = dsp[e] / cden;
    }
    int lane = tid & 63, wv = tid >> 6;
#pragma unroll
    for (int e = 0; e < 8; e++) {
        double s = (double)dsp[e];
#pragma unroll
        for (int off = 1; off < 64; off <<= 1) s += __shfl_xor(s, off, 64);
        if (lane == 0) wred[wv][e] = s;
    }
    __syncthreads();
    if (tid < 8) {
        double s = wred[0][tid] + wred[1][tid] + wred[2][tid] + wred[3][tid];
        atomicAdd(&loadAcc[tid], s);
    }
}

// ----------------------------------------------------------------------------
__global__ void penalty_k(const double* __restrict__ loadAcc, float* __restrict__ outp) {
    if (threadIdx.x == 0) {
        const float thr = (float)(2048.0 / 7.0 * 1.5);  // fair * 1.5
        float pen = 0.f;
#pragma unroll
        for (int e = 1; e < 8; e++) {
            float load = (float)(loadAcc[e] / 4.0);     // mean over B
            float x = fmaxf(load - thr, 0.f);
            pen += x * x;
        }
        outp[131072] = 0.01f * pen;
    }
}

// ----------------------------------------------------------------------------
extern "C" void kernel_launch(void* const* d_in, const int* in_sizes, int n_in,
                              void* d_out, int out_size, void* d_ws, size_t ws_size,
                              hipStream_t stream)
{
    const float* tokens = (const float*)d_in[0];
    const float* outA   = (const float*)d_in[1];
    const float* outC   = (const float*)d_in[2];
    const int*   tt     = (const int*)  d_in[3];
    const float* in_w   = (const float*)d_in[4];
    const float* in_b   = (const float*)d_in[5];
    const float* op_w   = (const float*)d_in[6];
    const float* op_b   = (const float*)d_in[7];
    const float* lng    = (const float*)d_in[8];
    const float* lnb    = (const float*)d_in[9];
    const float* te_w1  = (const float*)d_in[10];
    const float* te_b1  = (const float*)d_in[11];
    const float* te_w2  = (const float*)d_in[12];
    const float* te_b2  = (const float*)d_in[13];
    const float* g_w1   = (const float*)d_in[14];
    const float* g_b1   = (const float*)d_in[15];
    const float* g_w2   = (const float*)d_in[16];
    const float* g_b2   = (const float*)d_in[17];
    const float* e_bias = (const float*)d_in[18];
    float* out = (float*)d_out;

    float* ws = (float*)d_ws;
    const size_t NM = (size_t)8192 * 1024;
    float* F0     = ws;                  // out_proj result, then gate hidden (fp32)
    float* temb   = ws + NM;             // 4x1024 fp32
    float* embb   = temb + 4096;
    float* hte    = embb + 4096;         // 4x2048
    float* logitsb = hte + 8192;         // 8192x8
    double* loads = (double*)(logitsb + 65536);   // 8 doubles (+pad)

    u16* U = (u16*)(loads + 16);
    u16* Tokh = U;                 // tokens planes (alive whole launch)
    u16* Tokl = Tokh + NM;
    u16* ActH = Tokl + NM;         // [outA;outC] planes for K/V GEMMs
    u16* ActL = ActH + NM;
    u16* Qh   = ActL + NM;         // Q planes -> attn ctx planes (block-disjoint alias)
    u16* Ql   = Qh + NM;
    u16* Kh   = Ql + NM;           // K planes -> later LN(ctx_B) planes
    u16* Kl   = Kh + NM;
    u16* Vth  = Kl + NM;           // V^T planes [b][h][d][2048]
    u16* Vtl  = Vth + NM;
    u16* Wsh  = Vtl + NM;          // weight planes (up to 3M elems)
    u16* Wsl  = Wsh + (size_t)3 * 1024 * 1024;
    u16* Tbh  = Wsl + (size_t)3 * 1024 * 1024;   // temb planes, 4096
    u16* Tbl  = Tbh + 4096;

    zero_k<<<1, 64, 0, stream>>>(loads);
    emb_k<<<4, 512, 0, stream>>>(tt, embb);
    te_fc_k<<<dim3(4, 128), 256, 0, stream>>>(embb, te_w1, te_b1, hte, 1024, 2048, 1);
    te_fc_k<<<dim3(4, 64),  256, 0, stream>>>(hte,  te_w2, te_b2, temb, 2048, 1024, 0);

    split_k<<<8192, 256, 0, stream>>>(tokens, Tokh, Tokl, 8192 * 1024 / 4);
    split_k<<<3072, 256, 0, stream>>>(in_w, Wsh, Wsl, 3 * 1024 * 1024 / 4);
    split_k<<<4096, 256, 0, stream>>>(outA, ActH, ActL, 4096 * 1024 / 4);
    split_k<<<4096, 256, 0, stream>>>(outC, ActH + (size_t)4096 * 1024,
                                      ActL + (size_t)4096 * 1024, 4096 * 1024 / 4);

    // q = (tokens @ wq.T + bq) * (0.125*log2e) -> Q planes (softmax scale folded)
    bfgemm_k<false, false, 1><<<dim3(64, 8), 256, 0, stream>>>(
        Tokh, Tokl, nullptr, nullptr, nullptr, nullptr,
        Wsh, Wsl, in_b, nullptr, Qh, Ql, 1024, 0.18033688011112042f);
    // k -> K planes with per-batch concat row remap
    bfgemm_k<false, false, 2><<<dim3(64, 8), 256, 0, stream>>>(
        ActH, ActL, nullptr, nullptr, nullptr, nullptr,
        Wsh + (size_t)1024 * 1024, Wsl + (size_t)1024 * 1024,
        in_b + 1024, nullptr, Kh, Kl, 1024, 1.0f);
    // v^T: operands swapped (A = wv rows, "W" = act rows) -> transposed planes
    bfgemm_k<false, false, 3><<<dim3(8, 64), 256, 0, stream>>>(
        Wsh + (size_t)2048 * 1024, Wsl + (size_t)2048 * 1024,
        nullptr, nullptr, nullptr, nullptr,
        ActH, ActL, in_b + 2048, nullptr, Vth, Vtl, 1024, 1.0f);

    attn_k<<<dim3(64, 16), 256, 0, stream>>>(Qh, Ql, Kh, Kl, Vth, Vtl, Qh, Ql);

    // out_proj: ctx planes (in Qh/Ql) @ op_w -> fp32 F0
    split_k<<<1024, 256, 0, stream>>>(op_w, Wsh, Wsl, 1024 * 1024 / 4);
    bfgemm_k<false, false, 0><<<dim3(64, 8), 256, 0, stream>>>(
        Qh, Ql, nullptr, nullptr, nullptr, nullptr,
        Wsh, Wsl, op_b, F0, nullptr, nullptr, 1024, 1.0f);

    // ctx_B = LN(out_proj + tokens) -> planes (reuse K planes)
    ln_split_k<<<8192, 256, 0, stream>>>(F0, tokens, lng, lnb, Kh, Kl);

    // gate hidden = relu([tokens | ctx_B | t_emb] @ g_w1.T + b1) -> F0
    split_k<<<4, 256, 0, stream>>>(temb, Tbh, Tbl, 4096 / 4);
    split_k<<<3072, 256, 0, stream>>>(g_w1, Wsh, Wsl, 3072 * 1024 / 4);
    bfgemm_k<true, true, 0><<<dim3(64, 8), 256, 0, stream>>>(
        Tokh, Tokl, Kh, Kl, Tbh, Tbl,
        Wsh, Wsl, g_b1, F0, nullptr, nullptr, 3072, 1.0f);

    logits_k<<<2048, 256, 0, stream>>>(F0, g_w2, g_b2, e_bias, logitsb);
    router_k<<<32, 256, 0, stream>>>(logitsb, tt, out, loads);
    penalty_k<<<1, 64, 0, stream>>>(loads, out);
}

// Round 3
// 825.650 us; speedup vs baseline: 1.2201x; 1.0404x over previous
//
#include <hip/hip_runtime.h>
#include <math.h>

// Problem constants
//   B=4, NB=2048, NA=NC=1024, D=1024, E=8, H=16, HD=64, TOP_K=2
// R3 lesson: NO lambdas capturing register arrays in hot kernels (scratch spills).
// R4 lesson: transpose-store staging maps must be checked for bank collapse.
// R5: GEMMs on bf16 split-3 MFMA (hi*hi+hi*lo+lo*hi), err ~2^-16 — verified safe.
// R6: attention on split-3 MFMA. No-max softmax (scores bounded ~2.4, exp safe).
// R7 LESSON: __launch_bounds__(512,4) forced a 128-reg cap < ~150 live -> 1.4 GB
//     scratch spill. NEVER force occupancy past natural reg demand.
// R8 LESSON: P-read swizzle ((i*4+quad)<<3) only perturbs col bits 3-4 -> uint4
//     group index collapsed to 4 of 8 groups = 16 lanes/group (2x floor), +1.7e7
//     conflict cycles. Swizzles must be audited mod-32 PER ACCESS WIDTH.
// R9: attn 512-thr / q-tile 256 / double-buffered K,V via global_load_lds with
//     DMA issued at top of compute (latency hidden under full k-step) -> ONE
//     barrier per k-step (was 3). P [256][64] u32 separate region, chunk-XOR
//     swizzle phys_chunk = (col>>2) ^ (row&7): write 2/bank, read 8/group floor.
//     LDS 128 KB, 1 block/CU.

typedef __attribute__((ext_vector_type(8))) short short8;
typedef __attribute__((ext_vector_type(4))) float f32x4;
typedef __attribute__((ext_vector_type(4))) unsigned int u32x4;
typedef unsigned short u16;
typedef unsigned int u32;

// ----------------------------------------------------------------------------
__global__ void zero_k(double* p) {
    if (threadIdx.x < 8) p[threadIdx.x] = 0.0;
}

// ----------------------------------------------------------------------------
// fp32 -> bf16 hi/lo split helpers (RNE)
__device__ inline u16 bf_hi(float x) {
    u32 u = __float_as_uint(x);
    u += 0x7FFFu + ((u >> 16) & 1u);
    return (u16)(u >> 16);
}
__device__ inline u16 bf_lo(float x, u16 h) {
    float hf = __uint_as_float(((u32)h) << 16);
    return bf_hi(x - hf);
}
__device__ inline u32 pack_bf(float x) {
    u32 u = __float_as_uint(x);
    u32 hi = (u + (0x7FFFu + ((u >> 16) & 1u))) >> 16;
    float hf = __uint_as_float(hi << 16);
    float d = x - hf;
    u32 u2 = __float_as_uint(d);
    u32 lo = (u2 + (0x7FFFu + ((u2 >> 16) & 1u))) >> 16;
    return (hi << 16) | lo;
}

// fast pair-pack: two fp32 -> two (hi<<16|lo) u32 via v_cvt_pk_bf16_f32 + v_perm.
// Split-3 is robust to hi rounding mode: lo absorbs hi's rounding residual.
__device__ inline void pack2(float p0, float p1, u32& o0, u32& o1) {
    u32 h01, l01;
    asm("v_cvt_pk_bf16_f32 %0, %1, %2" : "=v"(h01) : "v"(p0), "v"(p1));
    float d0 = p0 - __uint_as_float(h01 << 16);
    float d1 = p1 - __uint_as_float(h01 & 0xffff0000u);
    asm("v_cvt_pk_bf16_f32 %0, %1, %2" : "=v"(l01) : "v"(d0), "v"(d1));
    o0 = __builtin_amdgcn_perm(h01, l01, 0x05040100u);   // [h0|l0]
    o1 = __builtin_amdgcn_perm(h01, l01, 0x07060302u);   // [h1|l1]
}

// async global->LDS, 16B per lane. LDS dest = wave-uniform base + lane*16.
__device__ inline void async16(const u16* g, u16* l) {
    __builtin_amdgcn_global_load_lds(
        (const __attribute__((address_space(1))) unsigned int*)g,
        (__attribute__((address_space(3))) unsigned int*)l,
        16, 0, 0);
}

__global__ __launch_bounds__(256)
void split_k(const float* __restrict__ in, u16* __restrict__ hi,
             u16* __restrict__ lo, int n4) {
    int i = blockIdx.x * 256 + threadIdx.x;
    if (i >= n4) return;
    float4 x = ((const float4*)in)[i];
    ushort4 h, l;
    h.x = bf_hi(x.x); l.x = bf_lo(x.x, h.x);
    h.y = bf_hi(x.y); l.y = bf_lo(x.y, h.y);
    h.z = bf_hi(x.z); l.z = bf_lo(x.z, h.z);
    h.w = bf_hi(x.w); l.w = bf_lo(x.w, h.w);
    ((ushort4*)hi)[i] = h;
    ((ushort4*)lo)[i] = l;
}

// ----------------------------------------------------------------------------
__global__ void emb_k(const int* __restrict__ t, float* __restrict__ emb) {
    int b = blockIdx.x;
    int j = threadIdx.x; // 0..511
    float x1 = (float)(-9.210340371976184) * (float)j;
    float x2 = x1 / 511.0f;
    float freq = (float)exp((double)x2);
    float tf = (float)t[b];
    float arg = tf * freq;
    emb[b * 1024 + j]       = (float)sin((double)arg);
    emb[b * 1024 + 512 + j] = (float)cos((double)arg);
}

// ----------------------------------------------------------------------------
__global__ void te_fc_k(const float* __restrict__ in, const float* __restrict__ W,
                        const float* __restrict__ bias, float* __restrict__ out,
                        int K, int N, int do_silu) {
    int b = blockIdx.x;
    int wv = threadIdx.x >> 6, lane = threadIdx.x & 63;
    const float* inb = in + (size_t)b * K;
    int n0 = blockIdx.y * 16 + wv * 4;
    for (int q = 0; q < 4; q++) {
        int n = n0 + q;
        const float* wr = W + (size_t)n * K;
        float acc = 0.f;
        for (int c = lane * 4; c < K; c += 256) {
            float4 a  = *(const float4*)(inb + c);
            float4 w4 = *(const float4*)(wr + c);
            acc += a.x * w4.x + a.y * w4.y + a.z * w4.z + a.w * w4.w;
        }
#pragma unroll
        for (int off = 1; off < 64; off <<= 1) acc += __shfl_xor(acc, off, 64);
        if (lane == 0) {
            float x = acc + bias[n];
            out[(size_t)b * N + n] = do_silu ? (x / (1.0f + expf(-x))) : x;
        }
    }
}

// ----------------------------------------------------------------------------
// bf16 split-3 MFMA GEMM. C[rr,cc] = (dot(A[rr,:K], W[cc,:K]) + bias) * scale.
// OMODE: 0 = fp32 out (identity rows), 1 = bf16 hi/lo planes (identity),
//        2 = bf16 planes with KV row remap (K proj), 3 = transposed V^T planes
//        (rows = v-col, cols = act rows; bias indexed by ROW).
template<bool GATE, bool RELU, int OMODE>
__global__ __launch_bounds__(256, 2)
void bfgemm_k(const u16* __restrict__ A0h, const u16* __restrict__ A0l,
              const u16* __restrict__ A1h, const u16* __restrict__ A1l,
              const u16* __restrict__ A2h, const u16* __restrict__ A2l,
              const u16* __restrict__ Wh_g, const u16* __restrict__ Wl_g,
              const float* __restrict__ bias, float* __restrict__ C,
              u16* __restrict__ Chi, u16* __restrict__ Clo, int K, float scale)
{
    __shared__ u16 Ah[128 * 32];
    __shared__ u16 Al[128 * 32];
    __shared__ u16 Wh[128 * 32];
    __shared__ u16 Wl[128 * 32];
    const int tid = threadIdx.x;
    const int row0 = blockIdx.x * 128;
    const int col0 = blockIdx.y * 128;
    const int wv = tid >> 6;
    const int lane = tid & 63;
    const int wrow = (wv & 1) * 64;
    const int wcol = (wv >> 1) * 64;
    const int l15 = lane & 15, quad = lane >> 4;

    f32x4 acc[4][4];
#pragma unroll
    for (int i = 0; i < 4; i++)
#pragma unroll
        for (int j = 0; j < 4; j++)
            acc[i][j] = (f32x4){0.f, 0.f, 0.f, 0.f};

    const int ar0 = tid >> 2, ak0 = (tid & 3) * 8;
    const int ar1 = (tid + 256) >> 2, ak1 = ((tid + 256) & 3) * 8;

    for (int kc = 0; kc < K; kc += 32) {
        const u16* pAh = A0h;
        const u16* pAl = A0l;
        int kk = kc;
        int tembseg = 0;
        if (GATE) {
            int seg = kc >> 10;
            if (seg == 1) { pAh = A1h; pAl = A1l; }
            else if (seg == 2) { pAh = A2h; pAl = A2l; tembseg = 1; }
            kk = kc & 1023;
        }
        const int astr = GATE ? 1024 : K;
        int g0 = row0 + ar0, g1 = row0 + ar1;
        if (GATE && tembseg) { g0 >>= 11; g1 >>= 11; }
        uint4 vah0 = *(const uint4*)&pAh[(size_t)g0 * astr + kk + ak0];
        uint4 vah1 = *(const uint4*)&pAh[(size_t)g1 * astr + kk + ak1];
        uint4 val0 = *(const uint4*)&pAl[(size_t)g0 * astr + kk + ak0];
        uint4 val1 = *(const uint4*)&pAl[(size_t)g1 * astr + kk + ak1];
        uint4 vwh0 = *(const uint4*)&Wh_g[(size_t)(col0 + ar0) * K + kc + ak0];
        uint4 vwh1 = *(const uint4*)&Wh_g[(size_t)(col0 + ar1) * K + kc + ak1];
        uint4 vwl0 = *(const uint4*)&Wl_g[(size_t)(col0 + ar0) * K + kc + ak0];
        uint4 vwl1 = *(const uint4*)&Wl_g[(size_t)(col0 + ar1) * K + kc + ak1];
        __syncthreads();
        *(uint4*)&Ah[ar0 * 32 + ak0] = vah0;
        *(uint4*)&Ah[ar1 * 32 + ak1] = vah1;
        *(uint4*)&Al[ar0 * 32 + ak0] = val0;
        *(uint4*)&Al[ar1 * 32 + ak1] = val1;
        *(uint4*)&Wh[ar0 * 32 + ak0] = vwh0;
        *(uint4*)&Wh[ar1 * 32 + ak1] = vwh1;
        *(uint4*)&Wl[ar0 * 32 + ak0] = vwl0;
        *(uint4*)&Wl[ar1 * 32 + ak1] = vwl1;
        __syncthreads();

        short8 a_h[4], a_l[4];
#pragma unroll
        for (int i = 0; i < 4; i++) {
            int r = (wrow + i * 16 + l15) * 32 + quad * 8;
            a_h[i] = *(const short8*)&Ah[r];
            a_l[i] = *(const short8*)&Al[r];
        }
#pragma unroll
        for (int j = 0; j < 4; j++) {
            int c = (wcol + j * 16 + l15) * 32 + quad * 8;
            short8 b_h = *(const short8*)&Wh[c];
            short8 b_l = *(const short8*)&Wl[c];
#pragma unroll
            for (int i = 0; i < 4; i++) {
                acc[i][j] = __builtin_amdgcn_mfma_f32_16x16x32_bf16(a_h[i], b_h, acc[i][j], 0, 0, 0);
                acc[i][j] = __builtin_amdgcn_mfma_f32_16x16x32_bf16(a_h[i], b_l, acc[i][j], 0, 0, 0);
                acc[i][j] = __builtin_amdgcn_mfma_f32_16x16x32_bf16(a_l[i], b_h, acc[i][j], 0, 0, 0);
            }
        }
    }

#pragma unroll
    for (int i = 0; i < 4; i++) {
#pragma unroll
        for (int j = 0; j < 4; j++) {
            int cc = col0 + wcol + j * 16 + l15;
#pragma unroll
            for (int r = 0; r < 4; r++) {
                int rr = row0 + wrow + i * 16 + quad * 4 + r;
                float v = (acc[i][j][r] + ((OMODE == 3) ? bias[rr] : bias[cc])) * scale;
                if (RELU) v = fmaxf(v, 0.f);
                if (OMODE == 0) {
                    C[(size_t)rr * 1024 + cc] = v;
                } else if (OMODE == 1) {
                    u32 pk = pack_bf(v);
                    size_t a = (size_t)rr * 1024 + cc;
                    Chi[a] = (u16)(pk >> 16); Clo[a] = (u16)pk;
                } else if (OMODE == 2) {
                    int orow = ((rr >> 10) & 3) * 2048 + (rr >> 12) * 1024 + (rr & 1023);
                    u32 pk = pack_bf(v);
                    size_t a = (size_t)orow * 1024 + cc;
                    Chi[a] = (u16)(pk >> 16); Clo[a] = (u16)pk;
                } else {
                    int bb2 = (cc >> 10) & 3;
                    int key = (cc >> 12) * 1024 + (cc & 1023);
                    u32 pk = pack_bf(v);
                    size_t a = ((size_t)(bb2 * 1024 + rr)) * 2048 + key;
                    Chi[a] = (u16)(pk >> 16); Clo[a] = (u16)pk;
                }
            }
        }
    }
}

// ----------------------------------------------------------------------------
// MFMA flash attention, split-3 bf16, no-max softmax.
// Block: 512 thr (8 waves), q-tile 256 (32 q/wave), k-tile 64, 32 k-steps.
// LDS 131072 B (1 block/CU): P [256][64] u32 chunk-XOR swizzled; K,V tiles
// DOUBLE-BUFFERED [2][hi/lo][64*64] u16 (row-chunk XOR swizzle).
// Pipeline: DMA(kt+1 -> buf^1) issued at top of compute(kt); single barrier
// per k-step drains DMA (latency hidden under the whole compute phase).
// Softmax: Q planes carry 0.125*log2e scale, so p = exp2(s) directly.
__global__ __launch_bounds__(512)
void attn_k(const u16* Qh, const u16* Ql,
            const u16* __restrict__ Kh, const u16* __restrict__ Kl,
            const u16* __restrict__ Vh, const u16* __restrict__ Vl,
            u16* Oh, u16* Ol)
{
    __shared__ u32 Pu[256 * 64];          // 65536 B
    __shared__ u16 Kb[2][2][64 * 64];     // 32768 B  [buf][hi/lo]
    __shared__ u16 Vb[2][2][64 * 64];     // 32768 B

    const int tid = threadIdx.x;
    const int w = tid >> 6, lane = tid & 63;
    const int l15 = lane & 15, quad = lane >> 4;
    const int bh = blockIdx.x, b = bh >> 4, h = bh & 15;
    const int qw = blockIdx.y * 256 + w * 32;          // local q base of this wave
    const int qrow0 = b * 2048 + qw;                    // global Q plane row base

    // Q A-fragments in registers
    short8 qh_f[2][2], ql_f[2][2];
#pragma unroll
    for (int i = 0; i < 2; i++)
#pragma unroll
        for (int kc = 0; kc < 2; kc++) {
            size_t a = (size_t)(qrow0 + i * 16 + l15) * 1024 + h * 64 + kc * 32 + quad * 8;
            qh_f[i][kc] = *(const short8*)&Qh[a];
            ql_f[i][kc] = *(const short8*)&Ql[a];
        }

    // async-staging maps: 512 thr cover a full 64-row tile per plane (one
    // async16 per plane per thread). LDS dest is linear (wave base + lane*16);
    // global source column carries the chunk swizzle c8 ^ (row&7).
    const int srow = tid >> 3;                        // 0..63
    const int scsw = ((tid & 7) ^ (srow & 7)) << 3;   // swizzled u16 col
    const size_t gk_base = ((size_t)(b * 2048) + srow) * 1024 + h * 64 + scsw;
    const size_t gv_base = ((size_t)((b * 16 + h) * 64 + srow)) * 2048 + scsw;

    f32x4 o[2][4];
#pragma unroll
    for (int i = 0; i < 2; i++)
#pragma unroll
        for (int j = 0; j < 4; j++) o[i][j] = (f32x4){0.f, 0.f, 0.f, 0.f};
    float lsum[2] = {0.f, 0.f};
    float lsv[2][4] = {};

    // prologue: stage tile 0 into buf 0
    {
        u16* kd = &Kb[0][0][0] + w * 512;
        u16* vd = &Vb[0][0][0] + w * 512;
        async16(&Kh[gk_base], kd);
        async16(&Kl[gk_base], kd + 4096);
        async16(&Vh[gv_base], vd);
        async16(&Vl[gv_base], vd + 4096);
    }
    __syncthreads();   // compiler drains vmcnt(0) before s_barrier -> tile 0 ready

    for (int kt = 0; kt < 32; kt++) {
        const int cur = kt & 1;
        // issue DMA for kt+1 into the other buffer; drains at loop-end barrier
        if (kt < 31) {
            const int nxt = cur ^ 1;
            const size_t gk = gk_base + (size_t)(kt + 1) * 65536;  // +64 keys
            const size_t gv = gv_base + (size_t)(kt + 1) * 64;     // +64 key-cols
            u16* kd = &Kb[0][0][0] + nxt * 8192 + w * 512;
            u16* vd = &Vb[0][0][0] + nxt * 8192 + w * 512;
            async16(&Kh[gk], kd);
            async16(&Kl[gk], kd + 4096);
            async16(&Vh[gv], vd);
            async16(&Vl[gv], vd + 4096);
        }
        const u16* Ksh = &Kb[0][0][0] + cur * 8192;
        const u16* Ksl = Ksh + 4096;
        const u16* Vs0 = &Vb[0][0][0] + cur * 8192;
        const u16* Vs1 = Vs0 + 4096;

        // QK^T
        f32x4 s[2][4];
#pragma unroll
        for (int i = 0; i < 2; i++)
#pragma unroll
            for (int j = 0; j < 4; j++) s[i][j] = (f32x4){0.f, 0.f, 0.f, 0.f};
#pragma unroll
        for (int j = 0; j < 4; j++) {
            int ka = (j * 16 + l15) * 64 + ((quad ^ (l15 & 7)) << 3);
            short8 kh0 = *(const short8*)&Ksh[ka];
            short8 kh1 = *(const short8*)&Ksh[ka ^ 32];
            short8 kl0 = *(const short8*)&Ksl[ka];
            short8 kl1 = *(const short8*)&Ksl[ka ^ 32];
#pragma unroll
            for (int i = 0; i < 2; i++) {
                s[i][j] = __builtin_amdgcn_mfma_f32_16x16x32_bf16(qh_f[i][0], kh0, s[i][j], 0, 0, 0);
                s[i][j] = __builtin_amdgcn_mfma_f32_16x16x32_bf16(qh_f[i][0], kl0, s[i][j], 0, 0, 0);
                s[i][j] = __builtin_amdgcn_mfma_f32_16x16x32_bf16(ql_f[i][0], kh0, s[i][j], 0, 0, 0);
                s[i][j] = __builtin_amdgcn_mfma_f32_16x16x32_bf16(qh_f[i][1], kh1, s[i][j], 0, 0, 0);
                s[i][j] = __builtin_amdgcn_mfma_f32_16x16x32_bf16(qh_f[i][1], kl1, s[i][j], 0, 0, 0);
                s[i][j] = __builtin_amdgcn_mfma_f32_16x16x32_bf16(ql_f[i][1], kh1, s[i][j], 0, 0, 0);
            }
        }
        // p = exp2(s) + pair-pack hi/lo + store P (chunk-XOR swizzle) + lsum.
        // No barrier: each wave reads back only its own P rows (in-wave lgkm
        // ordering), and P is a dedicated region (no K/V alias).
#pragma unroll
        for (int i = 0; i < 2; i++)
#pragma unroll
            for (int j = 0; j < 4; j++) {
                float p0 = exp2f(s[i][j][0]);
                float p1 = exp2f(s[i][j][1]);
                float p2 = exp2f(s[i][j][2]);
                float p3 = exp2f(s[i][j][3]);
                lsv[i][0] += p0; lsv[i][1] += p1;
                lsv[i][2] += p2; lsv[i][3] += p3;
                u32 o0, o1, o2, o3;
                pack2(p0, p1, o0, o1);
                pack2(p2, p3, o2, o3);
                int rb = w * 32 + i * 16 + quad * 4;
                int cq = (j * 4 + (l15 >> 2)) ^ ((quad & 1) << 2);
                int off = l15 & 3;
                Pu[(rb + 0) * 64 + ((cq ^ 0) << 2) + off] = o0;
                Pu[(rb + 1) * 64 + ((cq ^ 1) << 2) + off] = o1;
                Pu[(rb + 2) * 64 + ((cq ^ 2) << 2) + off] = o2;
                Pu[(rb + 3) * 64 + ((cq ^ 3) << 2) + off] = o3;
            }
        // PV: read own P rows (logical chunk k at phys chunk k ^ (row&7))
#pragma unroll
        for (int kc = 0; kc < 2; kc++) {
            short8 ph[2], pl[2];
#pragma unroll
            for (int i = 0; i < 2; i++) {
                int prow = w * 32 + i * 16 + l15;
                int x = l15 & 7;
                int k0 = kc * 8 + quad * 2;
                const u32* basep = &Pu[prow * 64];
                uint4 u0 = *(const uint4*)&basep[(k0 ^ x) << 2];
                uint4 u1 = *(const uint4*)&basep[((k0 + 1) ^ x) << 2];
                union { short8 s; u32x4 u; } hh, ll;
                hh.u = (u32x4){ __builtin_amdgcn_perm(u0.y, u0.x, 0x07060302u),
                                __builtin_amdgcn_perm(u0.w, u0.z, 0x07060302u),
                                __builtin_amdgcn_perm(u1.y, u1.x, 0x07060302u),
                                __builtin_amdgcn_perm(u1.w, u1.z, 0x07060302u) };
                ll.u = (u32x4){ __builtin_amdgcn_perm(u0.y, u0.x, 0x05040100u),
                                __builtin_amdgcn_perm(u0.w, u0.z, 0x05040100u),
                                __builtin_amdgcn_perm(u1.y, u1.x, 0x05040100u),
                                __builtin_amdgcn_perm(u1.w, u1.z, 0x05040100u) };
                ph[i] = hh.s; pl[i] = ll.s;
            }
#pragma unroll
            for (int jd = 0; jd < 4; jd++) {
                int va = (jd * 16 + l15) * 64 + ((((kc << 2) + quad) ^ (l15 & 7)) << 3);
                short8 vvh = *(const short8*)&Vs0[va];
                short8 vvl = *(const short8*)&Vs1[va];
#pragma unroll
                for (int i = 0; i < 2; i++) {
                    o[i][jd] = __builtin_amdgcn_mfma_f32_16x16x32_bf16(ph[i], vvh, o[i][jd], 0, 0, 0);
                    o[i][jd] = __builtin_amdgcn_mfma_f32_16x16x32_bf16(ph[i], vvl, o[i][jd], 0, 0, 0);
                    o[i][jd] = __builtin_amdgcn_mfma_f32_16x16x32_bf16(pl[i], vvh, o[i][jd], 0, 0, 0);
                }
            }
        }
        __syncthreads();   // all reads of buf[cur] done; DMA(kt+1) drained
    }
    // reduce lsum across the 16 key-lanes (xor 1,2,4,8 stay within quad rows)
#pragma unroll
    for (int i = 0; i < 2; i++)
#pragma unroll
        for (int r = 0; r < 4; r++) {
            float s2 = lsv[i][r];
            s2 += __shfl_xor(s2, 1, 64);
            s2 += __shfl_xor(s2, 2, 64);
            s2 += __shfl_xor(s2, 4, 64);
            s2 += __shfl_xor(s2, 8, 64);
            lsv[i][r] = s2;
        }
    (void)lsum;
    // epilogue: ctx = o / l -> bf16 hi/lo planes (overwrites this block's Q region)
#pragma unroll
    for (int i = 0; i < 2; i++)
#pragma unroll
        for (int jd = 0; jd < 4; jd++)
#pragma unroll
            for (int r = 0; r < 4; r++) {
                float v = o[i][jd][r] / lsv[i][r];
                u32 pk = pack_bf(v);
                size_t a = (size_t)(qrow0 + i * 16 + quad * 4 + r) * 1024 + h * 64 + jd * 16 + l15;
                Oh[a] = (u16)(pk >> 16);
                Ol[a] = (u16)pk;
            }
}

// ----------------------------------------------------------------------------
// layernorm(X + T) * g + b, emitting bf16 hi/lo planes for the gate GEMM
__global__ __launch_bounds__(256)
void ln_split_k(const float* __restrict__ X, const float* __restrict__ T,
                const float* __restrict__ g, const float* __restrict__ bta,
                u16* __restrict__ chi, u16* __restrict__ clo)
{
    __shared__ float red[8];
    int r = blockIdx.x, tid = threadIdx.x;
    size_t base = (size_t)r * 1024 + tid * 4;
    float4 x  = *(const float4*)(X + base);
    float4 tk = *(const float4*)(T + base);
    x.x += tk.x; x.y += tk.y; x.z += tk.z; x.w += tk.w;
    float s = x.x + x.y + x.z + x.w;
#pragma unroll
    for (int off = 1; off < 64; off <<= 1) s += __shfl_xor(s, off, 64);
    int wv = tid >> 6;
    if ((tid & 63) == 0) red[wv] = s;
    __syncthreads();
    float mu = (red[0] + red[1] + red[2] + red[3]) * (1.0f / 1024.0f);
    float dx0 = x.x - mu, dx1 = x.y - mu, dx2 = x.z - mu, dx3 = x.w - mu;
    float ss = dx0 * dx0 + dx1 * dx1 + dx2 * dx2 + dx3 * dx3;
#pragma unroll
    for (int off = 1; off < 64; off <<= 1) ss += __shfl_xor(ss, off, 64);
    if ((tid & 63) == 0) red[4 + wv] = ss;
    __syncthreads();
    float var = (red[4] + red[5] + red[6] + red[7]) * (1.0f / 1024.0f);
    float inv = 1.0f / sqrtf(var + 1e-5f);
    float4 gg = *(const float4*)(g + tid * 4);
    float4 bb = *(const float4*)(bta + tid * 4);
    float y0 = dx0 * inv * gg.x + bb.x;
    float y1 = dx1 * inv * gg.y + bb.y;
    float y2 = dx2 * inv * gg.z + bb.z;
    float y3 = dx3 * inv * gg.w + bb.w;
    ushort4 h, l;
    h.x = bf_hi(y0); l.x = bf_lo(y0, h.x);
    h.y = bf_hi(y1); l.y = bf_lo(y1, h.y);
    h.z = bf_hi(y2); l.z = bf_lo(y2, h.z);
    h.w = bf_hi(y3); l.w = bf_lo(y3, h.w);
    *(ushort4*)&chi[base] = h;
    *(ushort4*)&clo[base] = l;
}

// ----------------------------------------------------------------------------
__global__ __launch_bounds__(256)
void logits_k(const float* __restrict__ Hd, const float* __restrict__ W2,
              const float* __restrict__ b2, const float* __restrict__ eb,
              float* __restrict__ Lg)
{
    int gw = (blockIdx.x * 256 + threadIdx.x) >> 6;  // row 0..8191
    int lane = threadIdx.x & 63;
    const float* h = Hd + (size_t)gw * 1024;
    float4 hv[4];
#pragma unroll
    for (int j = 0; j < 4; j++) hv[j] = *(const float4*)(h + j * 256 + lane * 4);
    float res[8];
#pragma unroll
    for (int e = 0; e < 8; e++) {
        const float* w = W2 + (size_t)e * 1024;
        float acc = 0.f;
#pragma unroll
        for (int j = 0; j < 4; j++) {
            float4 w4 = *(const float4*)(w + j * 256 + lane * 4);
            acc += hv[j].x * w4.x + hv[j].y * w4.y + hv[j].z * w4.z + hv[j].w * w4.w;
        }
#pragma unroll
        for (int off = 1; off < 64; off <<= 1) acc += __shfl_xor(acc, off, 64);
        res[e] = acc;
    }
    if (lane < 8) {
        float v = res[0];
#pragma unroll
        for (int e = 1; e < 8; e++) v = (lane == e) ? res[e] : v;
        Lg[(size_t)gw * 8 + lane] = v + b2[lane] + eb[lane];
    }
}

// ----------------------------------------------------------------------------
__global__ __launch_bounds__(256)
void router_k(const float* __restrict__ Lg, const int* __restrict__ t,
              float* __restrict__ outp, double* __restrict__ loadAcc)
{
    __shared__ double wred[4][8];
    int tid = threadIdx.x;
    int r = blockIdx.x * 256 + tid;   // 0..8191
    int b = r >> 11;
    float tn  = (float)t[b] / 1000.0f;
    float tau = 0.5f + 1.5f * tn;
    float p[8];
    float mx = -INFINITY;
#pragma unroll
    for (int e = 0; e < 8; e++) { p[e] = Lg[(size_t)r * 8 + e] / tau; mx = fmaxf(mx, p[e]); }
    float sum = 0.f;
#pragma unroll
    for (int e = 0; e < 8; e++) { p[e] = expf(p[e] - mx); sum += p[e]; }
#pragma unroll
    for (int e = 0; e < 8; e++) p[e] = p[e] / sum;
#pragma unroll
    for (int e = 0; e < 8; e++) p[e] = 0.85f * p[e] + 0.01875f;   // (1-ALPHA)p + ALPHA/E
    float w = 0.1f + 0.1f * tn;
    float shared_p = fmaxf(p[0], w);
    float osum = 0.f;
#pragma unroll
    for (int e = 1; e < 8; e++) osum += p[e];
    float denom_o = fmaxf(osum, 1e-8f);
    float one_m = 1.0f - shared_p;
    p[0] = shared_p;
#pragma unroll
    for (int e = 1; e < 8; e++) p[e] = (p[e] / denom_o) * one_m;  // match np op order
    int i0 = 0; float v0 = p[0];
#pragma unroll
    for (int e = 1; e < 8; e++) if (p[e] > v0) { v0 = p[e]; i0 = e; }
    int i1 = -1; float v1 = -INFINITY;
#pragma unroll
    for (int e = 0; e < 8; e++) if (e != i0 && p[e] > v1) { v1 = p[e]; i1 = e; }
    float cap = 0.5f + 0.1f * tn;
    float dsp[8], capped[8], hr[8];
    float exsum = 0.f, hsum = 0.f;
#pragma unroll
    for (int e = 0; e < 8; e++) {
        float d = ((e == i0) ? v0 : 0.f) + ((e == i1) ? v1 : 0.f);
        float ex = fmaxf(d - cap, 0.f);
        float c = d - ex;
        float hh = fmaxf(cap - c, 0.f);
        capped[e] = c; hr[e] = hh;
        exsum += ex; hsum += hh;
    }
    float hden = fmaxf(hsum, 1e-8f);
    float dsum = 0.f;
#pragma unroll
    for (int e = 0; e < 8; e++) {
        float d = capped[e] + exsum * (hr[e] / hden);
        dsp[e] = d; dsum += d;
    }
    float cden = dsum + 1e-8f;
#pragma unroll
    for (int e = 0; e < 8; e++) {
        outp[(size_t)r * 8 + e] = dsp[e];
        outp[65536 + (size_t)r * 8 + e] = dsp[e] / cden;
    }
    int lane = tid & 63, wv = tid >> 6;
#pragma unroll
    for (int e = 0; e < 8; e++) {
        double s = (double)dsp[e];
#pragma unroll
        for (int off = 1; off < 64; off <<= 1) s += __shfl_xor(s, off, 64);
        if (lane == 0) wred[wv][e] = s;
    }
    __syncthreads();
    if (tid < 8) {
        double s = wred[0][tid] + wred[1][tid] + wred[2][tid] + wred[3][tid];
        atomicAdd(&loadAcc[tid], s);
    }
}

// ----------------------------------------------------------------------------
__global__ void penalty_k(const double* __restrict__ loadAcc, float* __restrict__ outp) {
    if (threadIdx.x == 0) {
        const float thr = (float)(2048.0 / 7.0 * 1.5);  // fair * 1.5
        float pen = 0.f;
#pragma unroll
        for (int e = 1; e < 8; e++) {
            float load = (float)(loadAcc[e] / 4.0);     // mean over B
            float x = fmaxf(load - thr, 0.f);
            pen += x * x;
        }
        outp[131072] = 0.01f * pen;
    }
}

// ----------------------------------------------------------------------------
extern "C" void kernel_launch(void* const* d_in, const int* in_sizes, int n_in,
                              void* d_out, int out_size, void* d_ws, size_t ws_size,
                              hipStream_t stream)
{
    const float* tokens = (const float*)d_in[0];
    const float* outA   = (const float*)d_in[1];
    const float* outC   = (const float*)d_in[2];
    const int*   tt     = (const int*)  d_in[3];
    const float* in_w   = (const float*)d_in[4];
    const float* in_b   = (const float*)d_in[5];
    const float* op_w   = (const float*)d_in[6];
    const float* op_b   = (const float*)d_in[7];
    const float* lng    = (const float*)d_in[8];
    const float* lnb    = (const float*)d_in[9];
    const float* te_w1  = (const float*)d_in[10];
    const float* te_b1  = (const float*)d_in[11];
    const float* te_w2  = (const float*)d_in[12];
    const float* te_b2  = (const float*)d_in[13];
    const float* g_w1   = (const float*)d_in[14];
    const float* g_b1   = (const float*)d_in[15];
    const float* g_w2   = (const float*)d_in[16];
    const float* g_b2   = (const float*)d_in[17];
    const float* e_bias = (const float*)d_in[18];
    float* out = (float*)d_out;

    float* ws = (float*)d_ws;
    const size_t NM = (size_t)8192 * 1024;
    float* F0     = ws;                  // out_proj result, then gate hidden (fp32)
    float* temb   = ws + NM;             // 4x1024 fp32
    float* embb   = temb + 4096;
    float* hte    = embb + 4096;         // 4x2048
    float* logitsb = hte + 8192;         // 8192x8
    double* loads = (double*)(logitsb + 65536);   // 8 doubles (+pad)

    u16* U = (u16*)(loads + 16);
    u16* Tokh = U;                 // tokens planes (alive whole launch)
    u16* Tokl = Tokh + NM;
    u16* ActH = Tokl + NM;         // [outA;outC] planes for K/V GEMMs
    u16* ActL = ActH + NM;
    u16* Qh   = ActL + NM;         // Q planes -> attn ctx planes (block-disjoint alias)
    u16* Ql   = Qh + NM;
    u16* Kh   = Ql + NM;           // K planes -> later LN(ctx_B) planes
    u16* Kl   = Kh + NM;
    u16* Vth  = Kl + NM;           // V^T planes [b][h][d][2048]
    u16* Vtl  = Vth + NM;
    u16* Wsh  = Vtl + NM;          // weight planes (up to 3M elems)
    u16* Wsl  = Wsh + (size_t)3 * 1024 * 1024;
    u16* Tbh  = Wsl + (size_t)3 * 1024 * 1024;   // temb planes, 4096
    u16* Tbl  = Tbh + 4096;

    zero_k<<<1, 64, 0, stream>>>(loads);
    emb_k<<<4, 512, 0, stream>>>(tt, embb);
    te_fc_k<<<dim3(4, 128), 256, 0, stream>>>(embb, te_w1, te_b1, hte, 1024, 2048, 1);
    te_fc_k<<<dim3(4, 64),  256, 0, stream>>>(hte,  te_w2, te_b2, temb, 2048, 1024, 0);

    split_k<<<8192, 256, 0, stream>>>(tokens, Tokh, Tokl, 8192 * 1024 / 4);
    split_k<<<3072, 256, 0, stream>>>(in_w, Wsh, Wsl, 3 * 1024 * 1024 / 4);
    split_k<<<4096, 256, 0, stream>>>(outA, ActH, ActL, 4096 * 1024 / 4);
    split_k<<<4096, 256, 0, stream>>>(outC, ActH + (size_t)4096 * 1024,
                                      ActL + (size_t)4096 * 1024, 4096 * 1024 / 4);

    // q = (tokens @ wq.T + bq) * (0.125*log2e) -> Q planes (softmax scale folded)
    bfgemm_k<false, false, 1><<<dim3(64, 8), 256, 0, stream>>>(
        Tokh, Tokl, nullptr, nullptr, nullptr, nullptr,
        Wsh, Wsl, in_b, nullptr, Qh, Ql, 1024, 0.18033688011112042f);
    // k -> K planes with per-batch concat row remap
    bfgemm_k<false, false, 2><<<dim3(64, 8), 256, 0, stream>>>(
        ActH, ActL, nullptr, nullptr, nullptr, nullptr,
        Wsh + (size_t)1024 * 1024, Wsl + (size_t)1024 * 1024,
        in_b + 1024, nullptr, Kh, Kl, 1024, 1.0f);
    // v^T: operands swapped (A = wv rows, "W" = act rows) -> transposed planes
    bfgemm_k<false, false, 3><<<dim3(8, 64), 256, 0, stream>>>(
        Wsh + (size_t)2048 * 1024, Wsl + (size_t)2048 * 1024,
        nullptr, nullptr, nullptr, nullptr,
        ActH, ActL, in_b + 2048, nullptr, Vth, Vtl, 1024, 1.0f);

    attn_k<<<dim3(64, 8), 512, 0, stream>>>(Qh, Ql, Kh, Kl, Vth, Vtl, Qh, Ql);

    // out_proj: ctx planes (in Qh/Ql) @ op_w -> fp32 F0
    split_k<<<1024, 256, 0, stream>>>(op_w, Wsh, Wsl, 1024 * 1024 / 4);
    bfgemm_k<false, false, 0><<<dim3(64, 8), 256, 0, stream>>>(
        Qh, Ql, nullptr, nullptr, nullptr, nullptr,
        Wsh, Wsl, op_b, F0, nullptr, nullptr, 1024, 1.0f);

    // ctx_B = LN(out_proj + tokens) -> planes (reuse K planes)
    ln_split_k<<<8192, 256, 0, stream>>>(F0, tokens, lng, lnb, Kh, Kl);

    // gate hidden = relu([tokens | ctx_B | t_emb] @ g_w1.T + b1) -> F0
    split_k<<<4, 256, 0, stream>>>(temb, Tbh, Tbl, 4096 / 4);
    split_k<<<3072, 256, 0, stream>>>(g_w1, Wsh, Wsl, 3072 * 1024 / 4);
    bfgemm_k<true, true, 0><<<dim3(64, 8), 256, 0, stream>>>(
        Tokh, Tokl, Kh, Kl, Tbh, Tbl,
        Wsh, Wsl, g_b1, F0, nullptr, nullptr, 3072, 1.0f);

    logits_k<<<2048, 256, 0, stream>>>(F0, g_w2, g_b2, e_bias, logitsb);
    router_k<<<32, 256, 0, stream>>>(logitsb, tt, out, loads);
    penalty_k<<<1, 64, 0, stream>>>(loads, out);
}

// Round 5
// 819.778 us; speedup vs baseline: 1.2288x; 1.0072x over previous
//
#include <hip/hip_runtime.h>
#include <math.h>

// Problem constants
//   B=4, NB=2048, NA=NC=1024, D=1024, E=8, H=16, HD=64, TOP_K=2
// R3 lesson: NO lambdas capturing register arrays in hot kernels (scratch spills).
// R4 lesson: transpose-store staging maps must be checked for bank collapse.
// R5: GEMMs on bf16 split-3 MFMA (hi*hi+hi*lo+lo*hi), err ~2^-16 — verified safe.
// R6: attention on split-3 MFMA. No-max softmax (scores bounded ~2.4, exp safe).
// R7 LESSON: forcing occupancy past natural reg demand -> catastrophic spill.
// R8 LESSON: swizzles must be audited mod-32 PER ACCESS WIDTH.
// R9: single barrier/kt + dbuf K,V via global_load_lds; conflicts at b128 floor.
//     Still latency-bound at 2 waves/SIMD (128KB LDS -> 1 block/CU).
// R10: swapped-operand attention. A-frag and B-frag are lane-transposes, so
//     S^T = mfma(A=K_frag, B=Q_frag) with the SAME loads. exp(S^T) registers ARE
//     the 16x16x16 B-fragment of P^T -> PV straight from regs (no P LDS at all).
//     PV: O^T += mfma16(V^T_frag, P^T_frag), V^T b64 reads from existing tiles.
//     LDS 64KB (K+V dbuf only) -> 2 blocks/CU, 4 waves/SIMD; launch_bounds(512,4)
//     safe: natural live set ~103 < 128 cap. Epilogue transposes O^T via LDS
//     (aliases dead K/V region, XOR-swizzled, conflict-audited) -> 16B stores.
// R4(bench): GPUAcquisitionTimeout — R10 never measured; resubmitted unchanged
//     after paper re-audit (layouts, swizzle widths, reg budget, LDS fencing).

typedef __attribute__((ext_vector_type(8))) short short8;
typedef __attribute__((ext_vector_type(4))) short sh4;
typedef __attribute__((ext_vector_type(4))) float f32x4;
typedef __attribute__((ext_vector_type(4))) unsigned int u32x4;
typedef unsigned short u16;
typedef unsigned int u32;

// ----------------------------------------------------------------------------
__global__ void zero_k(double* p) {
    if (threadIdx.x < 8) p[threadIdx.x] = 0.0;
}

// ----------------------------------------------------------------------------
// fp32 -> bf16 hi/lo split helpers (RNE)
__device__ inline u16 bf_hi(float x) {
    u32 u = __float_as_uint(x);
    u += 0x7FFFu + ((u >> 16) & 1u);
    return (u16)(u >> 16);
}
__device__ inline u16 bf_lo(float x, u16 h) {
    float hf = __uint_as_float(((u32)h) << 16);
    return bf_hi(x - hf);
}
__device__ inline u32 pack_bf(float x) {
    u32 u = __float_as_uint(x);
    u32 hi = (u + (0x7FFFu + ((u >> 16) & 1u))) >> 16;
    float hf = __uint_as_float(hi << 16);
    float d = x - hf;
    u32 u2 = __float_as_uint(d);
    u32 lo = (u2 + (0x7FFFu + ((u2 >> 16) & 1u))) >> 16;
    return (hi << 16) | lo;
}

// fast pair-pack: two fp32 -> two (hi<<16|lo) u32 via v_cvt_pk_bf16_f32 + v_perm.
__device__ inline void pack2(float p0, float p1, u32& o0, u32& o1) {
    u32 h01, l01;
    asm("v_cvt_pk_bf16_f32 %0, %1, %2" : "=v"(h01) : "v"(p0), "v"(p1));
    float d0 = p0 - __uint_as_float(h01 << 16);
    float d1 = p1 - __uint_as_float(h01 & 0xffff0000u);
    asm("v_cvt_pk_bf16_f32 %0, %1, %2" : "=v"(l01) : "v"(d0), "v"(d1));
    o0 = __builtin_amdgcn_perm(h01, l01, 0x05040100u);   // [h0|l0]
    o1 = __builtin_amdgcn_perm(h01, l01, 0x07060302u);   // [h1|l1]
}

// exp2 of 4 scores -> split-3 bf16 P^T fragments (hi, lo) + lsum accumulate.
__device__ inline void pfrag(const f32x4 s, sh4& hi, sh4& lo, float& acc) {
    float p0 = exp2f(s[0]), p1 = exp2f(s[1]), p2 = exp2f(s[2]), p3 = exp2f(s[3]);
    acc += (p0 + p1) + (p2 + p3);
    u32 h01, h23, l01, l23;
    asm("v_cvt_pk_bf16_f32 %0, %1, %2" : "=v"(h01) : "v"(p0), "v"(p1));
    asm("v_cvt_pk_bf16_f32 %0, %1, %2" : "=v"(h23) : "v"(p2), "v"(p3));
    float d0 = p0 - __uint_as_float(h01 << 16);
    float d1 = p1 - __uint_as_float(h01 & 0xffff0000u);
    float d2 = p2 - __uint_as_float(h23 << 16);
    float d3 = p3 - __uint_as_float(h23 & 0xffff0000u);
    asm("v_cvt_pk_bf16_f32 %0, %1, %2" : "=v"(l01) : "v"(d0), "v"(d1));
    asm("v_cvt_pk_bf16_f32 %0, %1, %2" : "=v"(l23) : "v"(d2), "v"(d3));
    union { u32 u[2]; sh4 s4; } H, L;
    H.u[0] = h01; H.u[1] = h23;
    L.u[0] = l01; L.u[1] = l23;
    hi = H.s4; lo = L.s4;
}

__device__ inline f32x4 mfma32(short8 a, short8 b, f32x4 c) {
    return __builtin_amdgcn_mfma_f32_16x16x32_bf16(a, b, c, 0, 0, 0);
}
__device__ inline f32x4 mfma16(sh4 a, sh4 b, f32x4 c) {
#if __has_builtin(__builtin_amdgcn_mfma_f32_16x16x16bf16_1k)
    return __builtin_amdgcn_mfma_f32_16x16x16bf16_1k(a, b, c, 0, 0, 0);
#else
    asm volatile("v_mfma_f32_16x16x16_bf16 %0, %1, %2, %0"
                 : "+v"(c) : "v"(a), "v"(b));
    return c;
#endif
}

// async global->LDS, 16B per lane. LDS dest = wave-uniform base + lane*16.
__device__ inline void async16(const u16* g, u16* l) {
    __builtin_amdgcn_global_load_lds(
        (const __attribute__((address_space(1))) unsigned int*)g,
        (__attribute__((address_space(3))) unsigned int*)l,
        16, 0, 0);
}

__global__ __launch_bounds__(256)
void split_k(const float* __restrict__ in, u16* __restrict__ hi,
             u16* __restrict__ lo, int n4) {
    int i = blockIdx.x * 256 + threadIdx.x;
    if (i >= n4) return;
    float4 x = ((const float4*)in)[i];
    ushort4 h, l;
    h.x = bf_hi(x.x); l.x = bf_lo(x.x, h.x);
    h.y = bf_hi(x.y); l.y = bf_lo(x.y, h.y);
    h.z = bf_hi(x.z); l.z = bf_lo(x.z, h.z);
    h.w = bf_hi(x.w); l.w = bf_lo(x.w, h.w);
    ((ushort4*)hi)[i] = h;
    ((ushort4*)lo)[i] = l;
}

// ----------------------------------------------------------------------------
__global__ void emb_k(const int* __restrict__ t, float* __restrict__ emb) {
    int b = blockIdx.x;
    int j = threadIdx.x; // 0..511
    float x1 = (float)(-9.210340371976184) * (float)j;
    float x2 = x1 / 511.0f;
    float freq = (float)exp((double)x2);
    float tf = (float)t[b];
    float arg = tf * freq;
    emb[b * 1024 + j]       = (float)sin((double)arg);
    emb[b * 1024 + 512 + j] = (float)cos((double)arg);
}

// ----------------------------------------------------------------------------
__global__ void te_fc_k(const float* __restrict__ in, const float* __restrict__ W,
                        const float* __restrict__ bias, float* __restrict__ out,
                        int K, int N, int do_silu) {
    int b = blockIdx.x;
    int wv = threadIdx.x >> 6, lane = threadIdx.x & 63;
    const float* inb = in + (size_t)b * K;
    int n0 = blockIdx.y * 16 + wv * 4;
    for (int q = 0; q < 4; q++) {
        int n = n0 + q;
        const float* wr = W + (size_t)n * K;
        float acc = 0.f;
        for (int c = lane * 4; c < K; c += 256) {
            float4 a  = *(const float4*)(inb + c);
            float4 w4 = *(const float4*)(wr + c);
            acc += a.x * w4.x + a.y * w4.y + a.z * w4.z + a.w * w4.w;
        }
#pragma unroll
        for (int off = 1; off < 64; off <<= 1) acc += __shfl_xor(acc, off, 64);
        if (lane == 0) {
            float x = acc + bias[n];
            out[(size_t)b * N + n] = do_silu ? (x / (1.0f + expf(-x))) : x;
        }
    }
}

// ----------------------------------------------------------------------------
// bf16 split-3 MFMA GEMM. C[rr,cc] = (dot(A[rr,:K], W[cc,:K]) + bias) * scale.
// OMODE: 0 = fp32 out (identity rows), 1 = bf16 hi/lo planes (identity),
//        2 = bf16 planes with KV row remap (K proj), 3 = transposed V^T planes
//        (rows = v-col, cols = act rows; bias indexed by ROW).
template<bool GATE, bool RELU, int OMODE>
__global__ __launch_bounds__(256, 2)
void bfgemm_k(const u16* __restrict__ A0h, const u16* __restrict__ A0l,
              const u16* __restrict__ A1h, const u16* __restrict__ A1l,
              const u16* __restrict__ A2h, const u16* __restrict__ A2l,
              const u16* __restrict__ Wh_g, const u16* __restrict__ Wl_g,
              const float* __restrict__ bias, float* __restrict__ C,
              u16* __restrict__ Chi, u16* __restrict__ Clo, int K, float scale)
{
    __shared__ u16 Ah[128 * 32];
    __shared__ u16 Al[128 * 32];
    __shared__ u16 Wh[128 * 32];
    __shared__ u16 Wl[128 * 32];
    const int tid = threadIdx.x;
    const int row0 = blockIdx.x * 128;
    const int col0 = blockIdx.y * 128;
    const int wv = tid >> 6;
    const int lane = tid & 63;
    const int wrow = (wv & 1) * 64;
    const int wcol = (wv >> 1) * 64;
    const int l15 = lane & 15, quad = lane >> 4;

    f32x4 acc[4][4];
#pragma unroll
    for (int i = 0; i < 4; i++)
#pragma unroll
        for (int j = 0; j < 4; j++)
            acc[i][j] = (f32x4){0.f, 0.f, 0.f, 0.f};

    const int ar0 = tid >> 2, ak0 = (tid & 3) * 8;
    const int ar1 = (tid + 256) >> 2, ak1 = ((tid + 256) & 3) * 8;

    for (int kc = 0; kc < K; kc += 32) {
        const u16* pAh = A0h;
        const u16* pAl = A0l;
        int kk = kc;
        int tembseg = 0;
        if (GATE) {
            int seg = kc >> 10;
            if (seg == 1) { pAh = A1h; pAl = A1l; }
            else if (seg == 2) { pAh = A2h; pAl = A2l; tembseg = 1; }
            kk = kc & 1023;
        }
        const int astr = GATE ? 1024 : K;
        int g0 = row0 + ar0, g1 = row0 + ar1;
        if (GATE && tembseg) { g0 >>= 11; g1 >>= 11; }
        uint4 vah0 = *(const uint4*)&pAh[(size_t)g0 * astr + kk + ak0];
        uint4 vah1 = *(const uint4*)&pAh[(size_t)g1 * astr + kk + ak1];
        uint4 val0 = *(const uint4*)&pAl[(size_t)g0 * astr + kk + ak0];
        uint4 val1 = *(const uint4*)&pAl[(size_t)g1 * astr + kk + ak1];
        uint4 vwh0 = *(const uint4*)&Wh_g[(size_t)(col0 + ar0) * K + kc + ak0];
        uint4 vwh1 = *(const uint4*)&Wh_g[(size_t)(col0 + ar1) * K + kc + ak1];
        uint4 vwl0 = *(const uint4*)&Wl_g[(size_t)(col0 + ar0) * K + kc + ak0];
        uint4 vwl1 = *(const uint4*)&Wl_g[(size_t)(col0 + ar1) * K + kc + ak1];
        __syncthreads();
        *(uint4*)&Ah[ar0 * 32 + ak0] = vah0;
        *(uint4*)&Ah[ar1 * 32 + ak1] = vah1;
        *(uint4*)&Al[ar0 * 32 + ak0] = val0;
        *(uint4*)&Al[ar1 * 32 + ak1] = val1;
        *(uint4*)&Wh[ar0 * 32 + ak0] = vwh0;
        *(uint4*)&Wh[ar1 * 32 + ak1] = vwh1;
        *(uint4*)&Wl[ar0 * 32 + ak0] = vwl0;
        *(uint4*)&Wl[ar1 * 32 + ak1] = vwl1;
        __syncthreads();

        short8 a_h[4], a_l[4];
#pragma unroll
        for (int i = 0; i < 4; i++) {
            int r = (wrow + i * 16 + l15) * 32 + quad * 8;
            a_h[i] = *(const short8*)&Ah[r];
            a_l[i] = *(const short8*)&Al[r];
        }
#pragma unroll
        for (int j = 0; j < 4; j++) {
            int c = (wcol + j * 16 + l15) * 32 + quad * 8;
            short8 b_h = *(const short8*)&Wh[c];
            short8 b_l = *(const short8*)&Wl[c];
#pragma unroll
            for (int i = 0; i < 4; i++) {
                acc[i][j] = __builtin_amdgcn_mfma_f32_16x16x32_bf16(a_h[i], b_h, acc[i][j], 0, 0, 0);
                acc[i][j] = __builtin_amdgcn_mfma_f32_16x16x32_bf16(a_h[i], b_l, acc[i][j], 0, 0, 0);
                acc[i][j] = __builtin_amdgcn_mfma_f32_16x16x32_bf16(a_l[i], b_h, acc[i][j], 0, 0, 0);
            }
        }
    }

#pragma unroll
    for (int i = 0; i < 4; i++) {
#pragma unroll
        for (int j = 0; j < 4; j++) {
            int cc = col0 + wcol + j * 16 + l15;
#pragma unroll
            for (int r = 0; r < 4; r++) {
                int rr = row0 + wrow + i * 16 + quad * 4 + r;
                float v = (acc[i][j][r] + ((OMODE == 3) ? bias[rr] : bias[cc])) * scale;
                if (RELU) v = fmaxf(v, 0.f);
                if (OMODE == 0) {
                    C[(size_t)rr * 1024 + cc] = v;
                } else if (OMODE == 1) {
                    u32 pk = pack_bf(v);
                    size_t a = (size_t)rr * 1024 + cc;
                    Chi[a] = (u16)(pk >> 16); Clo[a] = (u16)pk;
                } else if (OMODE == 2) {
                    int orow = ((rr >> 10) & 3) * 2048 + (rr >> 12) * 1024 + (rr & 1023);
                    u32 pk = pack_bf(v);
                    size_t a = (size_t)orow * 1024 + cc;
                    Chi[a] = (u16)(pk >> 16); Clo[a] = (u16)pk;
                } else {
                    int bb2 = (cc >> 10) & 3;
                    int key = (cc >> 12) * 1024 + (cc & 1023);
                    u32 pk = pack_bf(v);
                    size_t a = ((size_t)(bb2 * 1024 + rr)) * 2048 + key;
                    Chi[a] = (u16)(pk >> 16); Clo[a] = (u16)pk;
                }
            }
        }
    }
}

// ----------------------------------------------------------------------------
// MFMA flash attention, split-3 bf16, no-max softmax, swapped operands.
// Block: 512 thr (8 waves), q-tile 256 (32 q/wave), k-tile 64, 32 k-steps.
// LDS 65536 B (2 blocks/CU): K,V tiles double-buffered, chunk-XOR swizzled.
// S^T = mfma32(A=K_frag, B=Q_frag); exp(S^T) regs are directly the P^T
// B-fragment of mfma16; O^T accumulated in regs; epilogue LDS transpose.
__global__ __launch_bounds__(512, 4)
void attn_k(const u16* Qh, const u16* Ql,
            const u16* __restrict__ Kh, const u16* __restrict__ Kl,
            const u16* __restrict__ Vh, const u16* __restrict__ Vl,
            u16* Oh, u16* Ol)
{
    __shared__ __align__(16) u16 smem[32768];   // 64 KB
    u16* Kbase = smem;              // [buf:2][plane:2][4096]
    u16* Vbase = smem + 16384;      // [buf:2][plane:2][4096]

    const int tid = threadIdx.x;
    const int w = tid >> 6, lane = tid & 63;
    const int l15 = lane & 15, quad = lane >> 4;
    const int bh = blockIdx.x, b = bh >> 4, h = bh & 15;
    const int qw = blockIdx.y * 256 + w * 32;          // local q base of this wave
    const int qrow0 = b * 2048 + qw;                    // global Q plane row base

    // Q fragments in registers: same loads as before; now used as the
    // B-operand (= Q^T) of the swapped QK^T.
    short8 qh_f[2][2], ql_f[2][2];
#pragma unroll
    for (int i = 0; i < 2; i++)
#pragma unroll
        for (int kc = 0; kc < 2; kc++) {
            size_t a = (size_t)(qrow0 + i * 16 + l15) * 1024 + h * 64 + kc * 32 + quad * 8;
            qh_f[i][kc] = *(const short8*)&Qh[a];
            ql_f[i][kc] = *(const short8*)&Ql[a];
        }

    // staging maps: linear LDS dest (wave base + lane*16); global source column
    // carries the chunk swizzle c8 ^ (row&7). 512 thr cover a 64-row tile/plane.
    const int srow = tid >> 3;                        // 0..63
    const int scsw = ((tid & 7) ^ (srow & 7)) << 3;   // swizzled u16 col
    const size_t gk_base = ((size_t)(b * 2048) + srow) * 1024 + h * 64 + scsw;
    const size_t gv_base = ((size_t)((b * 16 + h) * 64 + srow)) * 2048 + scsw;

    f32x4 o[4][2];                 // O^T accumulators: [d-tile][q-subtile]
#pragma unroll
    for (int dt = 0; dt < 4; dt++)
#pragma unroll
        for (int i = 0; i < 2; i++) o[dt][i] = (f32x4){0.f, 0.f, 0.f, 0.f};
    float lsum[2] = {0.f, 0.f};

    // prologue: stage tile 0 into buf 0
    {
        u16* kd = Kbase + w * 512;
        u16* vd = Vbase + w * 512;
        async16(&Kh[gk_base], kd);
        async16(&Kl[gk_base], kd + 4096);
        async16(&Vh[gv_base], vd);
        async16(&Vl[gv_base], vd + 4096);
    }
    __syncthreads();   // vmcnt drained before barrier -> tile 0 ready

    for (int kt = 0; kt < 32; kt++) {
        const int cur = kt & 1;
        if (kt < 31) {
            const int nxt = cur ^ 1;
            const size_t gk = gk_base + (size_t)(kt + 1) * 65536;  // +64 keys
            const size_t gv = gv_base + (size_t)(kt + 1) * 64;     // +64 key-cols
            u16* kd = Kbase + nxt * 8192 + w * 512;
            u16* vd = Vbase + nxt * 8192 + w * 512;
            async16(&Kh[gk], kd);
            async16(&Kl[gk], kd + 4096);
            async16(&Vh[gv], vd);
            async16(&Vl[gv], vd + 4096);
        }
        const u16* Ksh = Kbase + cur * 8192;
        const u16* Ksl = Ksh + 4096;
        const u16* Vsh = Vbase + cur * 8192;
        const u16* Vsl = Vsh + 4096;

#pragma unroll
        for (int jt = 0; jt < 4; jt++) {
            // swapped QK^T: st[i] holds S^T[key=jt*16+quad*4+r][q=i*16+l15]
            f32x4 st0 = (f32x4){0.f, 0.f, 0.f, 0.f};
            f32x4 st1 = (f32x4){0.f, 0.f, 0.f, 0.f};
            const int ka = (jt * 16 + l15) * 64 + ((quad ^ (l15 & 7)) << 3);
            short8 kh0 = *(const short8*)&Ksh[ka];
            short8 kh1 = *(const short8*)&Ksh[ka ^ 32];
            short8 kl0 = *(const short8*)&Ksl[ka];
            short8 kl1 = *(const short8*)&Ksl[ka ^ 32];
            st0 = mfma32(kh0, qh_f[0][0], st0);
            st0 = mfma32(kl0, qh_f[0][0], st0);
            st0 = mfma32(kh0, ql_f[0][0], st0);
            st0 = mfma32(kh1, qh_f[0][1], st0);
            st0 = mfma32(kl1, qh_f[0][1], st0);
            st0 = mfma32(kh1, ql_f[0][1], st0);
            st1 = mfma32(kh0, qh_f[1][0], st1);
            st1 = mfma32(kl0, qh_f[1][0], st1);
            st1 = mfma32(kh0, ql_f[1][0], st1);
            st1 = mfma32(kh1, qh_f[1][1], st1);
            st1 = mfma32(kl1, qh_f[1][1], st1);
            st1 = mfma32(kh1, ql_f[1][1], st1);
            // exp2 (scale folded into Q) -> P^T fragments, straight in regs
            sh4 phi0, plo0, phi1, plo1;
            pfrag(st0, phi0, plo0, lsum[0]);
            pfrag(st1, phi1, plo1, lsum[1]);
            // PV: O^T[dt][i] += V^T-frag x P^T-frag (split-3)
#pragma unroll
            for (int dt = 0; dt < 4; dt++) {
                const int va = (dt * 16 + l15) * 64
                             + (((jt * 2 + (quad >> 1)) ^ (l15 & 7)) << 3)
                             + (quad & 1) * 4;
                sh4 vvh = *(const sh4*)&Vsh[va];
                sh4 vvl = *(const sh4*)&Vsl[va];
                o[dt][0] = mfma16(vvh, phi0, o[dt][0]);
                o[dt][0] = mfma16(vvl, phi0, o[dt][0]);
                o[dt][0] = mfma16(vvh, plo0, o[dt][0]);
                o[dt][1] = mfma16(vvh, phi1, o[dt][1]);
                o[dt][1] = mfma16(vvl, phi1, o[dt][1]);
                o[dt][1] = mfma16(vvh, plo1, o[dt][1]);
            }
        }
        __syncthreads();   // all reads of buf[cur] done; DMA(kt+1) drained
    }

    // lsum: sum over k -> reduce across the 4 quads (q = i*16+l15 per lane)
#pragma unroll
    for (int i = 0; i < 2; i++) {
        float s2 = lsum[i];
        s2 += __shfl_xor(s2, 16, 64);
        s2 += __shfl_xor(s2, 32, 64);
        lsum[i] = 1.0f / s2;
    }

    // epilogue: O^T -> O via in-LDS transpose (aliases dead K/V region; the
    // final loop barrier synced all waves). Per-wave 8KB region, XOR-swizzled:
    // write b64 2 lanes/bank, read b128 8 lanes/4-bank group (floor).
    u32* otr = (u32*)smem + w * 2048;
#pragma unroll
    for (int i = 0; i < 2; i++) {
        const int q = i * 16 + l15;
        const int xm = (q & 7) << 2;
#pragma unroll
        for (int dt = 0; dt < 4; dt++) {
#pragma unroll
            for (int r = 0; r < 4; r += 2) {
                float v0 = o[dt][i][r]     * lsum[i];
                float v1 = o[dt][i][r + 1] * lsum[i];
                u32 a0, a1;
                pack2(v0, v1, a0, a1);
                const int d = dt * 16 + quad * 4 + r;
                uint2 val; val.x = a0; val.y = a1;
                *(uint2*)&otr[q * 64 + (d ^ xm)] = val;
            }
        }
    }
    // same-wave read-back (in-wave lgkm ordering suffices)
    const int qr = lane >> 1;      // 0..31
    const int dh = lane & 1;
    const size_t gq = (size_t)(qrow0 + qr) * 1024 + h * 64 + dh * 32;
#pragma unroll
    for (int g = 0; g < 4; g++) {
        const int c0 = dh * 8 + g * 2;
        const int m = qr & 7;
        uint4 x = *(const uint4*)&otr[qr * 64 + ((c0 ^ m) << 2)];
        uint4 y = *(const uint4*)&otr[qr * 64 + (((c0 + 1) ^ m) << 2)];
        union { short8 s; u32x4 u; } hh, ll;
        hh.u = (u32x4){ __builtin_amdgcn_perm(x.y, x.x, 0x07060302u),
                        __builtin_amdgcn_perm(x.w, x.z, 0x07060302u),
                        __builtin_amdgcn_perm(y.y, y.x, 0x07060302u),
                        __builtin_amdgcn_perm(y.w, y.z, 0x07060302u) };
        ll.u = (u32x4){ __builtin_amdgcn_perm(x.y, x.x, 0x05040100u),
                        __builtin_amdgcn_perm(x.w, x.z, 0x05040100u),
                        __builtin_amdgcn_perm(y.y, y.x, 0x05040100u),
                        __builtin_amdgcn_perm(y.w, y.z, 0x05040100u) };
        *(short8*)&Oh[gq + g * 8] = hh.s;
        *(short8*)&Ol[gq + g * 8] = ll.s;
    }
}

// ----------------------------------------------------------------------------
// layernorm(X + T) * g + b, emitting bf16 hi/lo planes for the gate GEMM
__global__ __launch_bounds__(256)
void ln_split_k(const float* __restrict__ X, const float* __restrict__ T,
                const float* __restrict__ g, const float* __restrict__ bta,
                u16* __restrict__ chi, u16* __restrict__ clo)
{
    __shared__ float red[8];
    int r = blockIdx.x, tid = threadIdx.x;
    size_t base = (size_t)r * 1024 + tid * 4;
    float4 x  = *(const float4*)(X + base);
    float4 tk = *(const float4*)(T + base);
    x.x += tk.x; x.y += tk.y; x.z += tk.z; x.w += tk.w;
    float s = x.x + x.y + x.z + x.w;
#pragma unroll
    for (int off = 1; off < 64; off <<= 1) s += __shfl_xor(s, off, 64);
    int wv = tid >> 6;
    if ((tid & 63) == 0) red[wv] = s;
    __syncthreads();
    float mu = (red[0] + red[1] + red[2] + red[3]) * (1.0f / 1024.0f);
    float dx0 = x.x - mu, dx1 = x.y - mu, dx2 = x.z - mu, dx3 = x.w - mu;
    float ss = dx0 * dx0 + dx1 * dx1 + dx2 * dx2 + dx3 * dx3;
#pragma unroll
    for (int off = 1; off < 64; off <<= 1) ss += __shfl_xor(ss, off, 64);
    if ((tid & 63) == 0) red[4 + wv] = ss;
    __syncthreads();
    float var = (red[4] + red[5] + red[6] + red[7]) * (1.0f / 1024.0f);
    float inv = 1.0f / sqrtf(var + 1e-5f);
    float4 gg = *(const float4*)(g + tid * 4);
    float4 bb = *(const float4*)(bta + tid * 4);
    float y0 = dx0 * inv * gg.x + bb.x;
    float y1 = dx1 * inv * gg.y + bb.y;
    float y2 = dx2 * inv * gg.z + bb.z;
    float y3 = dx3 * inv * gg.w + bb.w;
    ushort4 h, l;
    h.x = bf_hi(y0); l.x = bf_lo(y0, h.x);
    h.y = bf_hi(y1); l.y = bf_lo(y1, h.y);
    h.z = bf_hi(y2); l.z = bf_lo(y2, h.z);
    h.w = bf_hi(y3); l.w = bf_lo(y3, h.w);
    *(ushort4*)&chi[base] = h;
    *(ushort4*)&clo[base] = l;
}

// ----------------------------------------------------------------------------
__global__ __launch_bounds__(256)
void logits_k(const float* __restrict__ Hd, const float* __restrict__ W2,
              const float* __restrict__ b2, const float* __restrict__ eb,
              float* __restrict__ Lg)
{
    int gw = (blockIdx.x * 256 + threadIdx.x) >> 6;  // row 0..8191
    int lane = threadIdx.x & 63;
    const float* h = Hd + (size_t)gw * 1024;
    float4 hv[4];
#pragma unroll
    for (int j = 0; j < 4; j++) hv[j] = *(const float4*)(h + j * 256 + lane * 4);
    float res[8];
#pragma unroll
    for (int e = 0; e < 8; e++) {
        const float* w = W2 + (size_t)e * 1024;
        float acc = 0.f;
#pragma unroll
        for (int j = 0; j < 4; j++) {
            float4 w4 = *(const float4*)(w + j * 256 + lane * 4);
            acc += hv[j].x * w4.x + hv[j].y * w4.y + hv[j].z * w4.z + hv[j].w * w4.w;
        }
#pragma unroll
        for (int off = 1; off < 64; off <<= 1) acc += __shfl_xor(acc, off, 64);
        res[e] = acc;
    }
    if (lane < 8) {
        float v = res[0];
#pragma unroll
        for (int e = 1; e < 8; e++) v = (lane == e) ? res[e] : v;
        Lg[(size_t)gw * 8 + lane] = v + b2[lane] + eb[lane];
    }
}

// ----------------------------------------------------------------------------
__global__ __launch_bounds__(256)
void router_k(const float* __restrict__ Lg, const int* __restrict__ t,
              float* __restrict__ outp, double* __restrict__ loadAcc)
{
    __shared__ double wred[4][8];
    int tid = threadIdx.x;
    int r = blockIdx.x * 256 + tid;   // 0..8191
    int b = r >> 11;
    float tn  = (float)t[b] / 1000.0f;
    float tau = 0.5f + 1.5f * tn;
    float p[8];
    float mx = -INFINITY;
#pragma unroll
    for (int e = 0; e < 8; e++) { p[e] = Lg[(size_t)r * 8 + e] / tau; mx = fmaxf(mx, p[e]); }
    float sum = 0.f;
#pragma unroll
    for (int e = 0; e < 8; e++) { p[e] = expf(p[e] - mx); sum += p[e]; }
#pragma unroll
    for (int e = 0; e < 8; e++) p[e] = p[e] / sum;
#pragma unroll
    for (int e = 0; e < 8; e++) p[e] = 0.85f * p[e] + 0.01875f;   // (1-ALPHA)p + ALPHA/E
    float w = 0.1f + 0.1f * tn;
    float shared_p = fmaxf(p[0], w);
    float osum = 0.f;
#pragma unroll
    for (int e = 1; e < 8; e++) osum += p[e];
    float denom_o = fmaxf(osum, 1e-8f);
    float one_m = 1.0f - shared_p;
    p[0] = shared_p;
#pragma unroll
    for (int e = 1; e < 8; e++) p[e] = (p[e] / denom_o) * one_m;  // match np op order
    int i0 = 0; float v0 = p[0];
#pragma unroll
    for (int e = 1; e < 8; e++) if (p[e] > v0) { v0 = p[e]; i0 = e; }
    int i1 = -1; float v1 = -INFINITY;
#pragma unroll
    for (int e = 0; e < 8; e++) if (e != i0 && p[e] > v1) { v1 = p[e]; i1 = e; }
    float cap = 0.5f + 0.1f * tn;
    float dsp[8], capped[8], hr[8];
    float exsum = 0.f, hsum = 0.f;
#pragma unroll
    for (int e = 0; e < 8; e++) {
        float d = ((e == i0) ? v0 : 0.f) + ((e == i1) ? v1 : 0.f);
        float ex = fmaxf(d - cap, 0.f);
        float c = d - ex;
        float hh = fmaxf(cap - c, 0.f);
        capped[e] = c; hr[e] = hh;
        exsum += ex; hsum += hh;
    }
    float hden = fmaxf(hsum, 1e-8f);
    float dsum = 0.f;
#pragma unroll
    for (int e = 0; e < 8; e++) {
        float d = capped[e] + exsum * (hr[e] / hden);
        dsp[e] = d; dsum += d;
    }
    float cden = dsum + 1e-8f;
#pragma unroll
    for (int e = 0; e < 8; e++) {
        outp[(size_t)r * 8 + e] = dsp[e];
        outp[65536 + (size_t)r * 8 + e] = dsp[e] / cden;
    }
    int lane = tid & 63, wv = tid >> 6;
#pragma unroll
    for (int e = 0; e < 8; e++) {
        double s = (double)dsp[e];
#pragma unroll
        for (int off = 1; off < 64; off <<= 1) s += __shfl_xor(s, off, 64);
        if (lane == 0) wred[wv][e] = s;
    }
    __syncthreads();
    if (tid < 8) {
        double s = wred[0][tid] + wred[1][tid] + wred[2][tid] + wred[3][tid];
        atomicAdd(&loadAcc[tid], s);
    }
}

// ----------------------------------------------------------------------------
__global__ void penalty_k(const double* __restrict__ loadAcc, float* __restrict__ outp) {
    if (threadIdx.x == 0) {
        const float thr = (float)(2048.0 / 7.0 * 1.5);  // fair * 1.5
        float pen = 0.f;
#pragma unroll
        for (int e = 1; e < 8; e++) {
            float load = (float)(loadAcc[e] / 4.0);     // mean over B
            float x = fmaxf(load - thr, 0.f);
            pen += x * x;
        }
        outp[131072] = 0.01f * pen;
    }
}

// ----------------------------------------------------------------------------
extern "C" void kernel_launch(void* const* d_in, const int* in_sizes, int n_in,
                              void* d_out, int out_size, void* d_ws, size_t ws_size,
                              hipStream_t stream)
{
    const float* tokens = (const float*)d_in[0];
    const float* outA   = (const float*)d_in[1];
    const float* outC   = (const float*)d_in[2];
    const int*   tt     = (const int*)  d_in[3];
    const float* in_w   = (const float*)d_in[4];
    const float* in_b   = (const float*)d_in[5];
    const float* op_w   = (const float*)d_in[6];
    const float* op_b   = (const float*)d_in[7];
    const float* lng    = (const float*)d_in[8];
    const float* lnb    = (const float*)d_in[9];
    const float* te_w1  = (const float*)d_in[10];
    const float* te_b1  = (const float*)d_in[11];
    const float* te_w2  = (const float*)d_in[12];
    const float* te_b2  = (const float*)d_in[13];
    const float* g_w1   = (const float*)d_in[14];
    const float* g_b1   = (const float*)d_in[15];
    const float* g_w2   = (const float*)d_in[16];
    const float* g_b2   = (const float*)d_in[17];
    const float* e_bias = (const float*)d_in[18];
    float* out = (float*)d_out;

    float* ws = (float*)d_ws;
    const size_t NM = (size_t)8192 * 1024;
    float* F0     = ws;                  // out_proj result, then gate hidden (fp32)
    float* temb   = ws + NM;             // 4x1024 fp32
    float* embb   = temb + 4096;
    float* hte    = embb + 4096;         // 4x2048
    float* logitsb = hte + 8192;         // 8192x8
    double* loads = (double*)(logitsb + 65536);   // 8 doubles (+pad)

    u16* U = (u16*)(loads + 16);
    u16* Tokh = U;                 // tokens planes (alive whole launch)
    u16* Tokl = Tokh + NM;
    u16* ActH = Tokl + NM;         // [outA;outC] planes for K/V GEMMs
    u16* ActL = ActH + NM;
    u16* Qh   = ActL + NM;         // Q planes -> attn ctx planes (block-disjoint alias)
    u16* Ql   = Qh + NM;
    u16* Kh   = Ql + NM;           // K planes -> later LN(ctx_B) planes
    u16* Kl   = Kh + NM;
    u16* Vth  = Kl + NM;           // V^T planes [b][h][d][2048]
    u16* Vtl  = Vth + NM;
    u16* Wsh  = Vtl + NM;          // weight planes (up to 3M elems)
    u16* Wsl  = Wsh + (size_t)3 * 1024 * 1024;
    u16* Tbh  = Wsl + (size_t)3 * 1024 * 1024;   // temb planes, 4096
    u16* Tbl  = Tbh + 4096;

    zero_k<<<1, 64, 0, stream>>>(loads);
    emb_k<<<4, 512, 0, stream>>>(tt, embb);
    te_fc_k<<<dim3(4, 128), 256, 0, stream>>>(embb, te_w1, te_b1, hte, 1024, 2048, 1);
    te_fc_k<<<dim3(4, 64),  256, 0, stream>>>(hte,  te_w2, te_b2, temb, 2048, 1024, 0);

    split_k<<<8192, 256, 0, stream>>>(tokens, Tokh, Tokl, 8192 * 1024 / 4);
    split_k<<<3072, 256, 0, stream>>>(in_w, Wsh, Wsl, 3 * 1024 * 1024 / 4);
    split_k<<<4096, 256, 0, stream>>>(outA, ActH, ActL, 4096 * 1024 / 4);
    split_k<<<4096, 256, 0, stream>>>(outC, ActH + (size_t)4096 * 1024,
                                      ActL + (size_t)4096 * 1024, 4096 * 1024 / 4);

    // q = (tokens @ wq.T + bq) * (0.125*log2e) -> Q planes (softmax scale folded)
    bfgemm_k<false, false, 1><<<dim3(64, 8), 256, 0, stream>>>(
        Tokh, Tokl, nullptr, nullptr, nullptr, nullptr,
        Wsh, Wsl, in_b, nullptr, Qh, Ql, 1024, 0.18033688011112042f);
    // k -> K planes with per-batch concat row remap
    bfgemm_k<false, false, 2><<<dim3(64, 8), 256, 0, stream>>>(
        ActH, ActL, nullptr, nullptr, nullptr, nullptr,
        Wsh + (size_t)1024 * 1024, Wsl + (size_t)1024 * 1024,
        in_b + 1024, nullptr, Kh, Kl, 1024, 1.0f);
    // v^T: operands swapped (A = wv rows, "W" = act rows) -> transposed planes
    bfgemm_k<false, false, 3><<<dim3(8, 64), 256, 0, stream>>>(
        Wsh + (size_t)2048 * 1024, Wsl + (size_t)2048 * 1024,
        nullptr, nullptr, nullptr, nullptr,
        ActH, ActL, in_b + 2048, nullptr, Vth, Vtl, 1024, 1.0f);

    attn_k<<<dim3(64, 8), 512, 0, stream>>>(Qh, Ql, Kh, Kl, Vth, Vtl, Qh, Ql);

    // out_proj: ctx planes (in Qh/Ql) @ op_w -> fp32 F0
    split_k<<<1024, 256, 0, stream>>>(op_w, Wsh, Wsl, 1024 * 1024 / 4);
    bfgemm_k<false, false, 0><<<dim3(64, 8), 256, 0, stream>>>(
        Qh, Ql, nullptr, nullptr, nullptr, nullptr,
        Wsh, Wsl, op_b, F0, nullptr, nullptr, 1024, 1.0f);

    // ctx_B = LN(out_proj + tokens) -> planes (reuse K planes)
    ln_split_k<<<8192, 256, 0, stream>>>(F0, tokens, lng, lnb, Kh, Kl);

    // gate hidden = relu([tokens | ctx_B | t_emb] @ g_w1.T + b1) -> F0
    split_k<<<4, 256, 0, stream>>>(temb, Tbh, Tbl, 4096 / 4);
    split_k<<<3072, 256, 0, stream>>>(g_w1, Wsh, Wsl, 3072 * 1024 / 4);
    bfgemm_k<true, true, 0><<<dim3(64, 8), 256, 0, stream>>>(
        Tokh, Tokl, Kh, Kl, Tbh, Tbl,
        Wsh, Wsl, g_b1, F0, nullptr, nullptr, 3072, 1.0f);

    logits_k<<<2048, 256, 0, stream>>>(F0, g_w2, g_b2, e_bias, logitsb);
    router_k<<<32, 256, 0, stream>>>(logitsb, tt, out, loads);
    penalty_k<<<1, 64, 0, stream>>>(loads, out);
}